// Round 3
// baseline (5473.825 us; speedup 1.0000x reference)
//
#include <hip/hip_runtime.h>
#include <hip/hip_bf16.h>

// ---------------- problem constants (fixed by reference) ----------------
#define NATOM 50000
#define NEDGE 200000
#define HALF  100000
#define DV    133
#define DE    14
#define DH    256
#define KVP   160   // pad 133 and 147 -> 160 (multiple of 32)
#define KOP   416   // pad 389 -> 416

typedef __bf16  bf16x8 __attribute__((ext_vector_type(8)));
typedef float   f32x4  __attribute__((ext_vector_type(4)));

enum { EPI_RELU = 0, EPI_ADDBASE = 1, EPI_FUSE = 2 };
enum { AM_PLAIN = 0, AM_GATE = 1, AM_GDIFF = 2 };

static __device__ __forceinline__ float b2f(unsigned short s) {
    union { float f; unsigned u; } x; x.u = ((unsigned)s) << 16; return x.f;
}

// ---------------- templated MFMA GEMM: C[rows,256] = epi(A' @ W[256,KP]^T) -----
// block = 256 threads = 4 waves; wave wv owns local rows [bx*64+wv*16, +16).
// Row mapping: local row gr -> global row (gr < part0 ? off0+gr : off1+gr-part0).
// A'-row (AMODE): PLAIN = A[gr] (local index); GATE = bf16(asum[g]*amax[g]);
//                 GDIFF = bf16(asum[vidx[g]] - Hb[rev[g]]).
// base/C indexed by global row (CLOC=0) or local row for temps (CLOC=1).
// STF32: store f32 (d_out) instead of bf16.
struct GArgs {
    const __bf16* A; int lda;
    const float* asum; const float* amax;
    const __bf16* HbG; const int* vidx; const int* rev;
    const __bf16* W; int ldw; int KP;
    const __bf16* base; __bf16* C; float* Cf;
    int Mloc; int part0; int off0; int off1;
};

template<int AMODE, int EPI, int CLOC, int STF32>
__global__ __launch_bounds__(256) void gemm_t(GArgs g) {
    const int lane = threadIdx.x & 63;
    const int wv   = threadIdx.x >> 6;
    const int quad = lane >> 4;
    const int l16  = lane & 15;
    const int gr0  = blockIdx.x * 64 + wv * 16;

    f32x4 acc[16];
#pragma unroll
    for (int i = 0; i < 16; ++i) acc[i] = (f32x4){0.f, 0.f, 0.f, 0.f};

    int grA = gr0 + l16; if (grA > g.Mloc - 1) grA = g.Mloc - 1;
    const int mapA = (grA < g.part0) ? g.off0 + grA : g.off1 + grA - g.part0;

    const __bf16* Ap = nullptr;
    const float *sp = nullptr, *mp = nullptr;
    const __bf16* hp = nullptr;
    if (AMODE == AM_PLAIN) {
        Ap = g.A + (size_t)grA * g.lda + quad * 8;
    } else if (AMODE == AM_GATE) {
        sp = g.asum + (size_t)mapA * DH + quad * 8;
        mp = g.amax + (size_t)mapA * DH + quad * 8;
    } else {
        int v = g.vidx[mapA], r = g.rev[mapA];
        sp = g.asum + (size_t)v * DH + quad * 8;
        hp = g.HbG  + (size_t)r * DH + quad * 8;
    }
    const __bf16* Wp = g.W + (size_t)l16 * g.ldw + quad * 8;

    const int ksteps = g.KP >> 5;
    for (int kk = 0; kk < ksteps; ++kk) {
        bf16x8 af;
        if (AMODE == AM_PLAIN) {
            af = *(const bf16x8*)(Ap + kk * 32);
        } else {
            f32x4 s0 = ((const f32x4*)(sp + kk * 32))[0];
            f32x4 s1 = ((const f32x4*)(sp + kk * 32))[1];
            if (AMODE == AM_GATE) {
                f32x4 m0 = ((const f32x4*)(mp + kk * 32))[0];
                f32x4 m1 = ((const f32x4*)(mp + kk * 32))[1];
#pragma unroll
                for (int j = 0; j < 4; ++j) {
                    af[j]     = (__bf16)(s0[j] * m0[j]);
                    af[4 + j] = (__bf16)(s1[j] * m1[j]);
                }
            } else {
                bf16x8 h = *(const bf16x8*)(hp + kk * 32);
#pragma unroll
                for (int j = 0; j < 4; ++j) {
                    af[j]     = (__bf16)(s0[j] - (float)h[j]);
                    af[4 + j] = (__bf16)(s1[j] - (float)h[4 + j]);
                }
            }
        }
#pragma unroll
        for (int nt = 0; nt < 16; ++nt) {
            bf16x8 bf = *(const bf16x8*)(Wp + (size_t)nt * 16 * g.ldw + kk * 32);
            acc[nt] = __builtin_amdgcn_mfma_f32_16x16x32_bf16(af, bf, acc[nt], 0, 0, 0);
        }
    }

#pragma unroll
    for (int nt = 0; nt < 16; ++nt) {
#pragma unroll
        for (int r = 0; r < 4; ++r) {
            int gr = gr0 + quad * 4 + r;
            if (gr < g.Mloc) {
                int mapped = (gr < g.part0) ? g.off0 + gr : g.off1 + gr - g.part0;
                int crow = CLOC ? gr : mapped;
                int col = nt * 16 + l16;
                size_t co = (size_t)crow * DH + col;
                float v = acc[nt][r];
                float res;
                if (EPI == EPI_RELU) {
                    res = v > 0.f ? v : 0.f;
                } else {
                    float b = (float)g.base[(size_t)mapped * DH + col];
                    res = (EPI == EPI_ADDBASE) ? (b + v) : (b + (v > 0.f ? v : 0.f));
                }
                if (STF32) g.Cf[co] = res;
                else       g.C[co]  = (__bf16)res;
            }
        }
    }
}

// ---------------- elementwise / prep kernels (f32 inputs -> bf16 internal) -----
__global__ void zero_f4(float* __restrict__ p, long n4) {
    long i = (long)blockIdx.x * blockDim.x + threadIdx.x;
    if (i < n4) ((f32x4*)p)[i] = (f32x4){0.f, 0.f, 0.f, 0.f};
}

__global__ void pad_w(const float* __restrict__ src, __bf16* __restrict__ dst, int KS, int KD) {
    int i = blockIdx.x * 256 + threadIdx.x;
    if (i >= 256 * KD) return;
    int n = i / KD, c = i - n * KD;
    dst[i] = (c < KS) ? (__bf16)src[n * KS + c] : (__bf16)0.f;
}

__global__ void pad_v(const float* __restrict__ V, __bf16* __restrict__ Vp) {
    int i = blockIdx.x * 256 + threadIdx.x;
    if (i >= NATOM * KVP) return;
    int n = i / KVP, c = i - n * KVP;
    Vp[i] = (c < DV) ? (__bf16)V[n * DV + c] : (__bf16)0.f;
}

__global__ void build_xb(const float* __restrict__ V, const float* __restrict__ Ef,
                         const int* __restrict__ vidx, __bf16* __restrict__ Xb) {
    long i = (long)blockIdx.x * 256 + threadIdx.x;
    if (i >= (long)NEDGE * KVP) return;
    int e = (int)(i / KVP), c = (int)(i - (long)e * KVP);
    __bf16 val;
    if (c < DV)            val = (__bf16)V[(size_t)vidx[e] * DV + c];
    else if (c < DV + DE)  val = (__bf16)Ef[(size_t)e * DE + (c - DV)];
    else                   val = (__bf16)0.f;
    Xb[i] = val;
}

// segment sum (+max) of H_b rows into atoms. H_b >= 0 (relu chain), so
// int-pattern atomicMax with 0-init is exact; empty segments stay 0 (matches ref).
__global__ void seg_accum(const __bf16* __restrict__ Hb, const int* __restrict__ widx,
                          float* __restrict__ asum, float* __restrict__ amax, int withMax) {
    long i = (long)blockIdx.x * 256 + threadIdx.x;   // NEDGE*64 threads, 4 cols each
    int e = (int)(i >> 6);
    if (e >= NEDGE) return;
    int c = ((int)i & 63) << 2;
    int a = widx[e];
    const unsigned* u = (const unsigned*)(Hb + (size_t)e * DH + c);
    unsigned u0 = u[0], u1 = u[1];
    float v0 = b2f(u0 & 0xffff), v1 = b2f(u0 >> 16);
    float v2 = b2f(u1 & 0xffff), v3 = b2f(u1 >> 16);
    float* spn = asum + (size_t)a * DH + c;
    atomicAdd(spn + 0, v0); atomicAdd(spn + 1, v1);
    atomicAdd(spn + 2, v2); atomicAdd(spn + 3, v3);
    if (withMax) {
        int* mpn = (int*)(amax + (size_t)a * DH + c);
        atomicMax(mpn + 0, __float_as_int(v0)); atomicMax(mpn + 1, __float_as_int(v1));
        atomicMax(mpn + 2, __float_as_int(v2)); atomicMax(mpn + 3, __float_as_int(v3));
    }
}

// Xo[NATOM, 416] = [ V (133) | bf16(a_sum) (256) | 0 pad ]
__global__ void build_xo(const float* __restrict__ V, const float* __restrict__ asum,
                         __bf16* __restrict__ Xo) {
    long i = (long)blockIdx.x * 256 + threadIdx.x;
    if (i >= (long)NATOM * KOP) return;
    int n = (int)(i / KOP), c = (int)(i - (long)n * KOP);
    __bf16 val;
    if (c < DV)            val = (__bf16)V[(size_t)n * DV + c];
    else if (c < DV + DH)  val = (__bf16)asum[(size_t)n * DH + (c - DV)];
    else                   val = (__bf16)0.f;
    Xo[i] = val;
}

// ---------------- launcher ----------------
static inline int cdiv(long a, long b) { return (int)((a + b - 1) / b); }

extern "C" void kernel_launch(void* const* d_in, const int* in_sizes, int n_in,
                              void* d_out, int out_size, void* d_ws, size_t ws_size,
                              hipStream_t stream) {
    const float* V    = (const float*)d_in[0];
    const float* Ef   = (const float*)d_in[1];
    const int*   ei   = (const int*)d_in[2];      // [0:E)=v, [E:2E)=w
    const int*   rev  = (const int*)d_in[3];
    const float* Wi_a = (const float*)d_in[4];    // [256,133]
    const float* Wi_b = (const float*)d_in[5];    // [256,147]
    const float* Wh_a = (const float*)d_in[6];    // [256,256]
    const float* Wh_b = (const float*)d_in[7];
    const float* Wf_a = (const float*)d_in[8];
    const float* Wf_b = (const float*)d_in[9];
    const float* Wo   = (const float*)d_in[10];   // [256,389]
    float* out = (float*)d_out;

    const int* vidx = ei;
    const int* widx = ei + NEDGE;

    // ---- workspace: fixed layout, total ~244.1 MB ----
    // Hb @0 (102.4M) | Ha @102.4M (25.6M) | S @128.0M (64.0M) | asum @192.0M (51.2M) | weights @243.2M
    // S lifetimes: prep Xb(64M) -> iter amax(51.2M)+Ta(12.8M) -> iter Tb(51.2M) -> readout Xo(41.6M)
    // Vp aliases asum (dead before asum first zeroed).
    char* ws = (char*)d_ws;
    __bf16* Hb   = (__bf16*)(ws + 0);
    __bf16* Ha   = (__bf16*)(ws + 102400000);
    char*   S    = ws + 128000000;
    float*  asum = (float*)(ws + 192000000);
    __bf16* Xb   = (__bf16*)(S + 0);
    float*  amax = (float*)(S + 0);
    __bf16* Ta   = (__bf16*)(S + 51200000);
    __bf16* Tb   = (__bf16*)(S + 0);
    __bf16* Xo   = (__bf16*)(S + 0);
    __bf16* Vp   = (__bf16*)asum;                 // 16M, dead before asum first zeroed
    __bf16* Wia  = (__bf16*)(ws + 243200000);     // 81,920
    __bf16* Wib  = (__bf16*)(ws + 243281920);     // 81,920
    __bf16* Wop  = (__bf16*)(ws + 243363840);     // 212,992
    __bf16* Wha  = (__bf16*)(ws + 243576832);     // 131,072
    __bf16* Whb  = (__bf16*)(ws + 243707904);     // 131,072
    __bf16* Wfa  = (__bf16*)(ws + 243838976);     // 131,072
    __bf16* Wfb  = (__bf16*)(ws + 243970048);     // 131,072 -> ends 244,101,120
    (void)ws_size;

    GArgs ga{};
    ga.asum = asum; ga.amax = amax; ga.HbG = Hb; ga.vidx = vidx; ga.rev = rev;

    // ---- prep: convert/pad all weights and inputs to bf16 ----
    pad_w<<<cdiv(256 * KVP, 256), 256, 0, stream>>>(Wi_a, Wia, DV, KVP);
    pad_w<<<cdiv(256 * KVP, 256), 256, 0, stream>>>(Wi_b, Wib, DV + DE, KVP);
    pad_w<<<cdiv(256 * KOP, 256), 256, 0, stream>>>(Wo, Wop, DV + DH, KOP);
    pad_w<<<cdiv(256 * DH, 256), 256, 0, stream>>>(Wh_a, Wha, DH, DH);
    pad_w<<<cdiv(256 * DH, 256), 256, 0, stream>>>(Wh_b, Whb, DH, DH);
    pad_w<<<cdiv(256 * DH, 256), 256, 0, stream>>>(Wf_a, Wfa, DH, DH);
    pad_w<<<cdiv(256 * DH, 256), 256, 0, stream>>>(Wf_b, Wfb, DH, DH);
    pad_v<<<cdiv((long)NATOM * KVP, 256), 256, 0, stream>>>(V, Vp);
    build_xb<<<cdiv((long)NEDGE * KVP, 256), 256, 0, stream>>>(V, Ef, vidx, Xb);

    // H_a = relu(Vp @ Wia^T)
    ga.A = Vp; ga.lda = KVP; ga.W = Wia; ga.ldw = KVP; ga.KP = KVP;
    ga.base = nullptr; ga.C = Ha; ga.Mloc = NATOM; ga.part0 = NATOM; ga.off0 = 0; ga.off1 = 0;
    gemm_t<AM_PLAIN, EPI_RELU, 0, 0><<<cdiv(NATOM, 64), 256, 0, stream>>>(ga);
    // H_b = relu(Xb @ Wib^T)
    ga.A = Xb; ga.W = Wib; ga.C = Hb; ga.Mloc = NEDGE; ga.part0 = NEDGE;
    gemm_t<AM_PLAIN, EPI_RELU, 0, 0><<<cdiv(NEDGE, 64), 256, 0, stream>>>(ga);

    // ---- message passing iterations ----
    for (int it = 0; it < 2; ++it) {
        zero_f4<<<cdiv((long)NATOM * DH / 4, 256), 256, 0, stream>>>(asum, (long)NATOM * DH / 4);
        zero_f4<<<cdiv((long)NATOM * DH / 4, 256), 256, 0, stream>>>(amax, (long)NATOM * DH / 4);
        seg_accum<<<cdiv((long)NEDGE * 64, 256), 256, 0, stream>>>(Hb, widx, asum, amax, 1);

        // atoms, 2 chunks of 25000 rows:
        //   Ta = Ha + bf16(asum*amax) @ Wh_a^T ; Ha += relu(Ta @ Wf_a^T)
        for (int c = 0; c < 2; ++c) {
            int off = c * 25000;
            ga.A = nullptr; ga.lda = DH; ga.W = Wha; ga.ldw = DH; ga.KP = DH;
            ga.base = Ha; ga.C = Ta; ga.Mloc = 25000; ga.part0 = 25000; ga.off0 = off; ga.off1 = 0;
            gemm_t<AM_GATE, EPI_ADDBASE, 1, 0><<<cdiv(25000, 64), 256, 0, stream>>>(ga);
            ga.A = Ta; ga.W = Wfa; ga.base = Ha; ga.C = Ha;
            gemm_t<AM_PLAIN, EPI_FUSE, 0, 0><<<cdiv(25000, 64), 256, 0, stream>>>(ga);
        }

        // bonds, 2 pair-closed chunks (rows [c*50K,+50K) U [100K+c*50K,+50K)):
        //   Tb = Hb + bf16(asum[v]-Hb[rev]) @ Wh_b^T ; Hb += relu(Tb @ Wf_b^T) in place.
        // rev maps within each chunk, so later chunks never read rows updated earlier.
        for (int c = 0; c < 2; ++c) {
            ga.A = nullptr; ga.lda = DH; ga.W = Whb; ga.ldw = DH; ga.KP = DH;
            ga.base = Hb; ga.C = Tb;
            ga.Mloc = 100000; ga.part0 = 50000; ga.off0 = c * 50000; ga.off1 = HALF + c * 50000;
            gemm_t<AM_GDIFF, EPI_ADDBASE, 1, 0><<<cdiv(100000, 64), 256, 0, stream>>>(ga);
            ga.A = Tb; ga.W = Wfb; ga.base = Hb; ga.C = Hb;
            gemm_t<AM_PLAIN, EPI_FUSE, 0, 0><<<cdiv(100000, 64), 256, 0, stream>>>(ga);
        }
    }

    // ---- readout ----
    zero_f4<<<cdiv((long)NATOM * DH / 4, 256), 256, 0, stream>>>(asum, (long)NATOM * DH / 4);
    seg_accum<<<cdiv((long)NEDGE * 64, 256), 256, 0, stream>>>(Hb, widx, asum, nullptr, 0);
    build_xo<<<cdiv((long)NATOM * KOP, 256), 256, 0, stream>>>(V, asum, Xo);
    ga.A = Xo; ga.lda = KOP; ga.W = Wop; ga.ldw = KOP; ga.KP = KOP;
    ga.base = nullptr; ga.C = nullptr; ga.Cf = out; ga.Mloc = NATOM; ga.part0 = NATOM; ga.off0 = 0; ga.off1 = 0;
    gemm_t<AM_PLAIN, EPI_RELU, 0, 1><<<cdiv(NATOM, 64), 256, 0, stream>>>(ga);
}

// Round 4
// 2578.194 us; speedup vs baseline: 2.1231x; 2.1231x over previous
//
#include <hip/hip_runtime.h>
#include <hip/hip_bf16.h>

// ---------------- problem constants (fixed by reference) ----------------
#define NATOM 50000
#define NEDGE 200000
#define HALF  100000
#define DV    133
#define DE    14
#define DH    256
#define KVP   160   // pad 133 and 147 -> 160 (multiple of 32)
#define KOP   416   // pad 389 -> 416

typedef __bf16  bf16x8 __attribute__((ext_vector_type(8)));
typedef __bf16  bf16x4 __attribute__((ext_vector_type(4)));
typedef float   f32x4  __attribute__((ext_vector_type(4)));

enum { EPI_RELU = 0, EPI_ADDBASE = 1, EPI_FUSE = 2 };
enum { AM_PLAIN = 0, AM_GATE = 1, AM_GDIFF = 2 };

// ---------------- templated MFMA GEMM: C[rows,256] = epi(A' @ W[256,KP]^T) -----
// block = 256 threads = 4 waves; wave wv owns local rows [bx*64+wv*16, +16).
// Row mapping: local row gr -> global row (gr < part0 ? off0+gr : off1+gr-part0).
// A'-row (AMODE): PLAIN = A[gr] (local index); GATE = bf16(asum[g]*amax[g]);
//                 GDIFF = bf16(asum[vidx[g]] - Hb[rev[g]]).
// base/C indexed by global row (CLOC=0) or local row for temps (CLOC=1).
// STF32: store f32 (d_out) instead of bf16.
struct GArgs {
    const __bf16* A; int lda;
    const float* asum; const float* amax;
    const __bf16* HbG; const int* vidx; const int* rev;
    const __bf16* W; int ldw; int KP;
    const __bf16* base; __bf16* C; float* Cf;
    int Mloc; int part0; int off0; int off1;
};

template<int AMODE, int EPI, int CLOC, int STF32>
__global__ __launch_bounds__(256) void gemm_t(GArgs g) {
    const int lane = threadIdx.x & 63;
    const int wv   = threadIdx.x >> 6;
    const int quad = lane >> 4;
    const int l16  = lane & 15;
    const int gr0  = blockIdx.x * 64 + wv * 16;

    f32x4 acc[16];
#pragma unroll
    for (int i = 0; i < 16; ++i) acc[i] = (f32x4){0.f, 0.f, 0.f, 0.f};

    int grA = gr0 + l16; if (grA > g.Mloc - 1) grA = g.Mloc - 1;
    const int mapA = (grA < g.part0) ? g.off0 + grA : g.off1 + grA - g.part0;

    const __bf16* Ap = nullptr;
    const float *sp = nullptr, *mp = nullptr;
    const __bf16* hp = nullptr;
    if (AMODE == AM_PLAIN) {
        Ap = g.A + (size_t)grA * g.lda + quad * 8;
    } else if (AMODE == AM_GATE) {
        sp = g.asum + (size_t)mapA * DH + quad * 8;
        mp = g.amax + (size_t)mapA * DH + quad * 8;
    } else {
        int v = g.vidx[mapA], r = g.rev[mapA];
        sp = g.asum + (size_t)v * DH + quad * 8;
        hp = g.HbG  + (size_t)r * DH + quad * 8;
    }
    const __bf16* Wp = g.W + (size_t)l16 * g.ldw + quad * 8;

    const int ksteps = g.KP >> 5;
    for (int kk = 0; kk < ksteps; ++kk) {
        bf16x8 af;
        if (AMODE == AM_PLAIN) {
            af = *(const bf16x8*)(Ap + kk * 32);
        } else {
            f32x4 s0 = ((const f32x4*)(sp + kk * 32))[0];
            f32x4 s1 = ((const f32x4*)(sp + kk * 32))[1];
            if (AMODE == AM_GATE) {
                f32x4 m0 = ((const f32x4*)(mp + kk * 32))[0];
                f32x4 m1 = ((const f32x4*)(mp + kk * 32))[1];
#pragma unroll
                for (int j = 0; j < 4; ++j) {
                    af[j]     = (__bf16)(s0[j] * m0[j]);
                    af[4 + j] = (__bf16)(s1[j] * m1[j]);
                }
            } else {
                bf16x8 h = *(const bf16x8*)(hp + kk * 32);
#pragma unroll
                for (int j = 0; j < 4; ++j) {
                    af[j]     = (__bf16)(s0[j] - (float)h[j]);
                    af[4 + j] = (__bf16)(s1[j] - (float)h[4 + j]);
                }
            }
        }
#pragma unroll
        for (int nt = 0; nt < 16; ++nt) {
            bf16x8 bf = *(const bf16x8*)(Wp + (size_t)nt * 16 * g.ldw + kk * 32);
            acc[nt] = __builtin_amdgcn_mfma_f32_16x16x32_bf16(af, bf, acc[nt], 0, 0, 0);
        }
    }

#pragma unroll
    for (int nt = 0; nt < 16; ++nt) {
#pragma unroll
        for (int r = 0; r < 4; ++r) {
            int gr = gr0 + quad * 4 + r;
            if (gr < g.Mloc) {
                int mapped = (gr < g.part0) ? g.off0 + gr : g.off1 + gr - g.part0;
                int crow = CLOC ? gr : mapped;
                int col = nt * 16 + l16;
                size_t co = (size_t)crow * DH + col;
                float v = acc[nt][r];
                float res;
                if (EPI == EPI_RELU) {
                    res = v > 0.f ? v : 0.f;
                } else {
                    float b = (float)g.base[(size_t)mapped * DH + col];
                    res = (EPI == EPI_ADDBASE) ? (b + v) : (b + (v > 0.f ? v : 0.f));
                }
                if (STF32) g.Cf[co] = res;
                else       g.C[co]  = (__bf16)res;
            }
        }
    }
}

// ---------------- CSR build (once per launch; widx constant) ----------------
__global__ void count_deg(const int* __restrict__ widx, int* __restrict__ cnt) {
    int e = blockIdx.x * 256 + threadIdx.x;
    if (e < NEDGE) atomicAdd(&cnt[widx[e]], 1);
}

// single-block exclusive scan over NATOM counts -> rowptr[NATOM+1]
__global__ __launch_bounds__(256) void scan_counts(const int* __restrict__ cnt,
                                                   int* __restrict__ rowptr) {
    __shared__ int partial[256];
    const int tid = threadIdx.x;
    const int CH = (NATOM + 255) / 256;   // 196
    const int base = tid * CH;
    int s = 0;
    for (int i = 0; i < CH; ++i) {
        int idx = base + i;
        if (idx < NATOM) s += cnt[idx];
    }
    partial[tid] = s;
    __syncthreads();
    for (int off = 1; off < 256; off <<= 1) {
        int v = (tid >= off) ? partial[tid - off] : 0;
        __syncthreads();
        partial[tid] += v;
        __syncthreads();
    }
    int run = (tid > 0) ? partial[tid - 1] : 0;
    for (int i = 0; i < CH; ++i) {
        int idx = base + i;
        if (idx < NATOM) { rowptr[idx] = run; run += cnt[idx]; }
    }
    if (tid == 255) rowptr[NATOM] = partial[255];
}

__global__ void fill_csr(const int* __restrict__ widx, int* __restrict__ cursor,
                         int* __restrict__ eid) {
    int e = blockIdx.x * 256 + threadIdx.x;
    if (e >= NEDGE) return;
    int pos = atomicAdd(&cursor[widx[e]], 1);
    eid[pos] = e;
}

// ---------------- segmented sum+max, one wave per atom, no atomics ----------
// lane owns cols [lane*4, lane*4+4). H_b >= 0 (relu chain) so max-init 0 is
// exact and empty segments give 0 (matches reference's isfinite->0 rule).
template<int WITHMAX>
__global__ __launch_bounds__(256) void seg_reduce(
    const __bf16* __restrict__ Hb, const int* __restrict__ rowptr,
    const int* __restrict__ eid,
    float* __restrict__ asum, float* __restrict__ amax)
{
    int a = blockIdx.x * 4 + (threadIdx.x >> 6);
    if (a >= NATOM) return;
    const int lane = threadIdx.x & 63;
    const int beg = rowptr[a], end = rowptr[a + 1];
    float s0 = 0.f, s1 = 0.f, s2 = 0.f, s3 = 0.f;
    float m0 = 0.f, m1 = 0.f, m2 = 0.f, m3 = 0.f;
    for (int i = beg; i < end; ++i) {
        int e = eid[i];
        bf16x4 h = *(const bf16x4*)(Hb + (size_t)e * DH + lane * 4);
        float v0 = (float)h[0], v1 = (float)h[1], v2 = (float)h[2], v3 = (float)h[3];
        s0 += v0; s1 += v1; s2 += v2; s3 += v3;
        if (WITHMAX) {
            m0 = fmaxf(m0, v0); m1 = fmaxf(m1, v1);
            m2 = fmaxf(m2, v2); m3 = fmaxf(m3, v3);
        }
    }
    size_t o = (size_t)a * DH + lane * 4;
    *(f32x4*)(asum + o) = (f32x4){s0, s1, s2, s3};
    if (WITHMAX) *(f32x4*)(amax + o) = (f32x4){m0, m1, m2, m3};
}

// ---------------- elementwise / prep kernels (f32 inputs -> bf16 internal) -----
__global__ void pad_w(const float* __restrict__ src, __bf16* __restrict__ dst, int KS, int KD) {
    int i = blockIdx.x * 256 + threadIdx.x;
    if (i >= 256 * KD) return;
    int n = i / KD, c = i - n * KD;
    dst[i] = (c < KS) ? (__bf16)src[n * KS + c] : (__bf16)0.f;
}

__global__ void pad_v(const float* __restrict__ V, __bf16* __restrict__ Vp) {
    int i = blockIdx.x * 256 + threadIdx.x;
    if (i >= NATOM * KVP) return;
    int n = i / KVP, c = i - n * KVP;
    Vp[i] = (c < DV) ? (__bf16)V[n * DV + c] : (__bf16)0.f;
}

__global__ void build_xb(const float* __restrict__ V, const float* __restrict__ Ef,
                         const int* __restrict__ vidx, __bf16* __restrict__ Xb) {
    long i = (long)blockIdx.x * 256 + threadIdx.x;
    if (i >= (long)NEDGE * KVP) return;
    int e = (int)(i / KVP), c = (int)(i - (long)e * KVP);
    __bf16 val;
    if (c < DV)            val = (__bf16)V[(size_t)vidx[e] * DV + c];
    else if (c < DV + DE)  val = (__bf16)Ef[(size_t)e * DE + (c - DV)];
    else                   val = (__bf16)0.f;
    Xb[i] = val;
}

// Xo[NATOM, 416] = [ V (133) | bf16(a_sum) (256) | 0 pad ]
__global__ void build_xo(const float* __restrict__ V, const float* __restrict__ asum,
                         __bf16* __restrict__ Xo) {
    long i = (long)blockIdx.x * 256 + threadIdx.x;
    if (i >= (long)NATOM * KOP) return;
    int n = (int)(i / KOP), c = (int)(i - (long)n * KOP);
    __bf16 val;
    if (c < DV)            val = (__bf16)V[(size_t)n * DV + c];
    else if (c < DV + DH)  val = (__bf16)asum[(size_t)n * DH + (c - DV)];
    else                   val = (__bf16)0.f;
    Xo[i] = val;
}

// ---------------- launcher ----------------
static inline int cdiv(long a, long b) { return (int)((a + b - 1) / b); }

extern "C" void kernel_launch(void* const* d_in, const int* in_sizes, int n_in,
                              void* d_out, int out_size, void* d_ws, size_t ws_size,
                              hipStream_t stream) {
    const float* V    = (const float*)d_in[0];
    const float* Ef   = (const float*)d_in[1];
    const int*   ei   = (const int*)d_in[2];      // [0:E)=v, [E:2E)=w
    const int*   rev  = (const int*)d_in[3];
    const float* Wi_a = (const float*)d_in[4];    // [256,133]
    const float* Wi_b = (const float*)d_in[5];    // [256,147]
    const float* Wh_a = (const float*)d_in[6];    // [256,256]
    const float* Wh_b = (const float*)d_in[7];
    const float* Wf_a = (const float*)d_in[8];
    const float* Wf_b = (const float*)d_in[9];
    const float* Wo   = (const float*)d_in[10];   // [256,389]
    float* out = (float*)d_out;

    const int* vidx = ei;
    const int* widx = ei + NEDGE;

    // ---- workspace: fixed layout, total ~245.4 MB ----
    // Hb @0 (102.4M) | Ha @102.4M (25.6M) | S @128.0M (64.0M) | asum @192.0M (51.2M)
    // | weights @243.2M | CSR @244.2M
    // S lifetimes: prep Xb(64M) -> iter amax(51.2M)+Ta(12.8M) -> iter Tb(51.2M) -> readout Xo(41.6M)
    // Vp aliases asum (dead before asum first written by seg_reduce).
    char* ws = (char*)d_ws;
    __bf16* Hb   = (__bf16*)(ws + 0);
    __bf16* Ha   = (__bf16*)(ws + 102400000);
    char*   S    = ws + 128000000;
    float*  asum = (float*)(ws + 192000000);
    __bf16* Xb   = (__bf16*)(S + 0);
    float*  amax = (float*)(S + 0);
    __bf16* Ta   = (__bf16*)(S + 51200000);
    __bf16* Tb   = (__bf16*)(S + 0);
    __bf16* Xo   = (__bf16*)(S + 0);
    __bf16* Vp   = (__bf16*)asum;                 // 16M, dead before asum first written
    __bf16* Wia  = (__bf16*)(ws + 243200000);     // 81,920
    __bf16* Wib  = (__bf16*)(ws + 243281920);     // 81,920
    __bf16* Wop  = (__bf16*)(ws + 243363840);     // 212,992
    __bf16* Wha  = (__bf16*)(ws + 243576832);     // 131,072
    __bf16* Whb  = (__bf16*)(ws + 243707904);     // 131,072
    __bf16* Wfa  = (__bf16*)(ws + 243838976);     // 131,072
    __bf16* Wfb  = (__bf16*)(ws + 243970048);     // 131,072 -> 244,101,120
    int*  rowptr = (int*)(ws + 244101120);        // 200,004 -> pad 200,192
    int*  cursor = (int*)(ws + 244301312);        // 200,000 (aliases deg counts)
    int*  eid    = (int*)(ws + 244501504);        // 800,000 -> ends 245,301,504
    (void)ws_size;

    GArgs ga{};
    ga.asum = asum; ga.amax = amax; ga.HbG = Hb; ga.vidx = vidx; ga.rev = rev;

    // ---- CSR build (widx fixed for whole launch) ----
    hipMemsetAsync(cursor, 0, NATOM * sizeof(int), stream);
    count_deg<<<cdiv(NEDGE, 256), 256, 0, stream>>>(widx, cursor);
    scan_counts<<<1, 256, 0, stream>>>(cursor, rowptr);
    hipMemcpyAsync(cursor, rowptr, NATOM * sizeof(int), hipMemcpyDeviceToDevice, stream);
    fill_csr<<<cdiv(NEDGE, 256), 256, 0, stream>>>(widx, cursor, eid);

    // ---- prep: convert/pad all weights and inputs to bf16 ----
    pad_w<<<cdiv(256 * KVP, 256), 256, 0, stream>>>(Wi_a, Wia, DV, KVP);
    pad_w<<<cdiv(256 * KVP, 256), 256, 0, stream>>>(Wi_b, Wib, DV + DE, KVP);
    pad_w<<<cdiv(256 * KOP, 256), 256, 0, stream>>>(Wo, Wop, DV + DH, KOP);
    pad_w<<<cdiv(256 * DH, 256), 256, 0, stream>>>(Wh_a, Wha, DH, DH);
    pad_w<<<cdiv(256 * DH, 256), 256, 0, stream>>>(Wh_b, Whb, DH, DH);
    pad_w<<<cdiv(256 * DH, 256), 256, 0, stream>>>(Wf_a, Wfa, DH, DH);
    pad_w<<<cdiv(256 * DH, 256), 256, 0, stream>>>(Wf_b, Wfb, DH, DH);
    pad_v<<<cdiv((long)NATOM * KVP, 256), 256, 0, stream>>>(V, Vp);
    build_xb<<<cdiv((long)NEDGE * KVP, 256), 256, 0, stream>>>(V, Ef, vidx, Xb);

    // H_a = relu(Vp @ Wia^T)
    ga.A = Vp; ga.lda = KVP; ga.W = Wia; ga.ldw = KVP; ga.KP = KVP;
    ga.base = nullptr; ga.C = Ha; ga.Mloc = NATOM; ga.part0 = NATOM; ga.off0 = 0; ga.off1 = 0;
    gemm_t<AM_PLAIN, EPI_RELU, 0, 0><<<cdiv(NATOM, 64), 256, 0, stream>>>(ga);
    // H_b = relu(Xb @ Wib^T)
    ga.A = Xb; ga.W = Wib; ga.C = Hb; ga.Mloc = NEDGE; ga.part0 = NEDGE;
    gemm_t<AM_PLAIN, EPI_RELU, 0, 0><<<cdiv(NEDGE, 64), 256, 0, stream>>>(ga);

    // ---- message passing iterations ----
    for (int it = 0; it < 2; ++it) {
        seg_reduce<1><<<cdiv(NATOM, 4), 256, 0, stream>>>(Hb, rowptr, eid, asum, amax);

        // atoms, 2 chunks of 25000 rows:
        //   Ta = Ha + bf16(asum*amax) @ Wh_a^T ; Ha += relu(Ta @ Wf_a^T)
        for (int c = 0; c < 2; ++c) {
            int off = c * 25000;
            ga.A = nullptr; ga.lda = DH; ga.W = Wha; ga.ldw = DH; ga.KP = DH;
            ga.base = Ha; ga.C = Ta; ga.Mloc = 25000; ga.part0 = 25000; ga.off0 = off; ga.off1 = 0;
            gemm_t<AM_GATE, EPI_ADDBASE, 1, 0><<<cdiv(25000, 64), 256, 0, stream>>>(ga);
            ga.A = Ta; ga.W = Wfa; ga.base = Ha; ga.C = Ha;
            gemm_t<AM_PLAIN, EPI_FUSE, 0, 0><<<cdiv(25000, 64), 256, 0, stream>>>(ga);
        }

        // bonds, 2 pair-closed chunks (rows [c*50K,+50K) U [100K+c*50K,+50K)):
        //   Tb = Hb + bf16(asum[v]-Hb[rev]) @ Wh_b^T ; Hb += relu(Tb @ Wf_b^T) in place.
        // rev maps within each chunk, so later chunks never read rows updated earlier.
        for (int c = 0; c < 2; ++c) {
            ga.A = nullptr; ga.lda = DH; ga.W = Whb; ga.ldw = DH; ga.KP = DH;
            ga.base = Hb; ga.C = Tb;
            ga.Mloc = 100000; ga.part0 = 50000; ga.off0 = c * 50000; ga.off1 = HALF + c * 50000;
            gemm_t<AM_GDIFF, EPI_ADDBASE, 1, 0><<<cdiv(100000, 64), 256, 0, stream>>>(ga);
            ga.A = Tb; ga.W = Wfb; ga.base = Hb; ga.C = Hb;
            gemm_t<AM_PLAIN, EPI_FUSE, 0, 0><<<cdiv(100000, 64), 256, 0, stream>>>(ga);
        }
    }

    // ---- readout ----
    seg_reduce<0><<<cdiv(NATOM, 4), 256, 0, stream>>>(Hb, rowptr, eid, asum, nullptr);
    build_xo<<<cdiv((long)NATOM * KOP, 256), 256, 0, stream>>>(V, asum, Xo);
    ga.A = Xo; ga.lda = KOP; ga.W = Wop; ga.ldw = KOP; ga.KP = KOP;
    ga.base = nullptr; ga.C = nullptr; ga.Cf = out; ga.Mloc = NATOM; ga.part0 = NATOM; ga.off0 = 0; ga.off1 = 0;
    gemm_t<AM_PLAIN, EPI_RELU, 0, 1><<<cdiv(NATOM, 64), 256, 0, stream>>>(ga);
}

// Round 5
// 1830.938 us; speedup vs baseline: 2.9896x; 1.4081x over previous
//
#include <hip/hip_runtime.h>
#include <hip/hip_bf16.h>

// ---------------- problem constants (fixed by reference) ----------------
#define NATOM 50000
#define NEDGE 200000
#define HALF  100000
#define DV    133
#define DE    14
#define DH    256
#define KVP   160   // pad 133/147 -> 160 (5 k-steps)

typedef __bf16  bf16x8 __attribute__((ext_vector_type(8)));
typedef __bf16  bf16x4 __attribute__((ext_vector_type(4)));
typedef float   f32x4  __attribute__((ext_vector_type(4)));

enum { EPI_RELU = 0, EPI_ADDBASE = 1, EPI_FUSE = 2, EPI_NONE = 3, EPI_RELUADD = 4 };
enum { AM_PLAIN = 0, AM_GATE = 1, AM_GDIFF = 2, AM_VF32 = 3, AM_XB = 4, AM_F32 = 5 };

// ---------------- B-stationary MFMA GEMM ----------------
// C[rows,256] = epi(A'[rows,K] @ W[256,K]^T).  Block = 4 waves; wave wv owns
// cols [wv*64, wv*64+64) and holds its whole W slice in registers
// (4 col-tiles x KSTEPS x 16B/lane = 64*KSTEPS VGPRs).  Grid-strides over
// 64-row chunks; per chunk each wave computes a 64x64 patch (16 f32x4 accs).
// Row map: local gr -> global (gr < part0 ? off0+gr : off1+gr-part0).
// A' synthesis per AMODE:
//   PLAIN: bf16 A[gr (local)]          GATE:  bf16(asum[g]*amax[g])
//   GDIFF: bf16(asum[vidx[g]]-Hb[rev[g]])
//   VF32:  bf16(V[g]) cols<133, pad    XB: [V[vidx[g]]|Ef[g]] cols<147, pad
//   F32:   bf16(asum[g])
struct GArgs {
    const __bf16* A; int lda;
    const float* asum; const __bf16* amaxb;
    const __bf16* HbG; const int* vidx; const int* rev;
    const float* Vf; const float* Ef;
    const __bf16* W; int ldw;
    const __bf16* base; __bf16* C; float* Cf;
    int Mloc; int part0; int off0; int off1;
};

template<int AMODE, int EPI, int CLOC, int STF32, int KSTEPS>
__global__ __launch_bounds__(256, 2) void gemm_bs(GArgs g, int nch) {
    const int lane = threadIdx.x & 63;
    const int wv   = threadIdx.x >> 6;
    const int quad = lane >> 4;
    const int l16  = lane & 15;
    const int colb = wv * 64;

    // ---- load stationary B slice ----
    bf16x8 bfr[4 * KSTEPS];
    {
        const __bf16* Wp = g.W + (size_t)(colb + l16) * g.ldw + quad * 8;
#pragma unroll
        for (int n = 0; n < 4; ++n)
#pragma unroll
            for (int k = 0; k < KSTEPS; ++k)
                bfr[n * KSTEPS + k] = *(const bf16x8*)(Wp + (size_t)(n * 16) * g.ldw + k * 32);
    }

    for (int ch = blockIdx.x; ch < nch; ch += gridDim.x) {
        const int gr0 = ch * 64;
        f32x4 acc[16];
#pragma unroll
        for (int i = 0; i < 16; ++i) acc[i] = (f32x4){0.f, 0.f, 0.f, 0.f};

#pragma unroll
        for (int m = 0; m < 4; ++m) {
            int grA = gr0 + m * 16 + l16; if (grA > g.Mloc - 1) grA = g.Mloc - 1;
            const int mapA = (grA < g.part0) ? g.off0 + grA : g.off1 + grA - g.part0;

            const __bf16* Ap = nullptr; const float* sp = nullptr;
            const __bf16* hp = nullptr; const __bf16* mp = nullptr;
            const float* vp_ = nullptr; const float* ep_ = nullptr;
            if (AMODE == AM_PLAIN) {
                Ap = g.A + (size_t)grA * g.lda + quad * 8;
            } else if (AMODE == AM_GATE) {
                sp = g.asum  + (size_t)mapA * DH + quad * 8;
                mp = g.amaxb + (size_t)mapA * DH + quad * 8;
            } else if (AMODE == AM_GDIFF) {
                int v = g.vidx[mapA], r = g.rev[mapA];
                sp = g.asum + (size_t)v * DH + quad * 8;
                hp = g.HbG  + (size_t)r * DH + quad * 8;
            } else if (AMODE == AM_VF32) {
                vp_ = g.Vf + (size_t)mapA * DV;
            } else if (AMODE == AM_XB) {
                vp_ = g.Vf + (size_t)g.vidx[mapA] * DV;
                ep_ = g.Ef + (size_t)mapA * DE;
            } else { // AM_F32
                sp = g.asum + (size_t)mapA * DH + quad * 8;
            }

#pragma unroll
            for (int k = 0; k < KSTEPS; ++k) {
                bf16x8 af;
                if (AMODE == AM_PLAIN) {
                    af = *(const bf16x8*)(Ap + k * 32);
                } else if (AMODE == AM_GATE || AMODE == AM_GDIFF || AMODE == AM_F32) {
                    f32x4 s0 = ((const f32x4*)(sp + k * 32))[0];
                    f32x4 s1 = ((const f32x4*)(sp + k * 32))[1];
                    if (AMODE == AM_GATE) {
                        bf16x8 mx = *(const bf16x8*)(mp + k * 32);
#pragma unroll
                        for (int j = 0; j < 4; ++j) {
                            af[j]     = (__bf16)(s0[j] * (float)mx[j]);
                            af[4 + j] = (__bf16)(s1[j] * (float)mx[4 + j]);
                        }
                    } else if (AMODE == AM_GDIFF) {
                        bf16x8 h = *(const bf16x8*)(hp + k * 32);
#pragma unroll
                        for (int j = 0; j < 4; ++j) {
                            af[j]     = (__bf16)(s0[j] - (float)h[j]);
                            af[4 + j] = (__bf16)(s1[j] - (float)h[4 + j]);
                        }
                    } else {
#pragma unroll
                        for (int j = 0; j < 4; ++j) {
                            af[j]     = (__bf16)s0[j];
                            af[4 + j] = (__bf16)s1[j];
                        }
                    }
                } else { // AM_VF32 / AM_XB: f32 source rows, width 133 (+14)
                    const int c0 = k * 32 + quad * 8;
                    if (k < 4) {    // cols <= 127, fully inside V row (4B-aligned)
                        f32x4 a, b;
                        __builtin_memcpy(&a, vp_ + c0, 16);
                        __builtin_memcpy(&b, vp_ + c0 + 4, 16);
#pragma unroll
                        for (int j = 0; j < 4; ++j) {
                            af[j]     = (__bf16)a[j];
                            af[4 + j] = (__bf16)b[j];
                        }
                    } else {        // boundary k-step: per-element guarded
#pragma unroll
                        for (int t = 0; t < 8; ++t) {
                            int c = c0 + t;
                            float x = 0.f;
                            if (c < DV)                          x = vp_[c];
                            else if (AMODE == AM_XB && c < DV + DE) x = ep_[c - DV];
                            af[t] = (__bf16)x;
                        }
                    }
                }
#pragma unroll
                for (int n = 0; n < 4; ++n)
                    acc[m * 4 + n] = __builtin_amdgcn_mfma_f32_16x16x32_bf16(
                        af, bfr[n * KSTEPS + k], acc[m * 4 + n], 0, 0, 0);
            }
        }

        // ---- epilogue: wave's 64x64 patch ----
#pragma unroll
        for (int m = 0; m < 4; ++m)
#pragma unroll
        for (int n = 0; n < 4; ++n)
#pragma unroll
        for (int r = 0; r < 4; ++r) {
            int gr = gr0 + m * 16 + quad * 4 + r;
            if (gr < g.Mloc) {
                int mapped = (gr < g.part0) ? g.off0 + gr : g.off1 + gr - g.part0;
                int crow = CLOC ? gr : mapped;
                int col = colb + n * 16 + l16;
                size_t co = (size_t)crow * DH + col;
                float v = acc[m * 4 + n][r];
                float res;
                if (EPI == EPI_RELU)       res = v > 0.f ? v : 0.f;
                else if (EPI == EPI_NONE)  res = v;
                else {
                    float b = (float)g.base[(size_t)mapped * DH + col];
                    if (EPI == EPI_ADDBASE)      res = b + v;
                    else if (EPI == EPI_FUSE)    res = b + (v > 0.f ? v : 0.f);
                    else /* EPI_RELUADD */       { res = b + v; res = res > 0.f ? res : 0.f; }
                }
                if (STF32) g.Cf[co] = res;
                else       g.C[co]  = (__bf16)res;
            }
        }
    }
}

// ---------------- CSR build (once per launch; widx constant) ----------------
__global__ void count_deg(const int* __restrict__ widx, int* __restrict__ cnt) {
    int e = blockIdx.x * 256 + threadIdx.x;
    if (e < NEDGE) atomicAdd(&cnt[widx[e]], 1);
}

__global__ __launch_bounds__(256) void scan_counts(const int* __restrict__ cnt,
                                                   int* __restrict__ rowptr) {
    __shared__ int partial[256];
    const int tid = threadIdx.x;
    const int CH = (NATOM + 255) / 256;
    const int base = tid * CH;
    int s = 0;
    for (int i = 0; i < CH; ++i) { int idx = base + i; if (idx < NATOM) s += cnt[idx]; }
    partial[tid] = s;
    __syncthreads();
    for (int off = 1; off < 256; off <<= 1) {
        int v = (tid >= off) ? partial[tid - off] : 0;
        __syncthreads();
        partial[tid] += v;
        __syncthreads();
    }
    int run = (tid > 0) ? partial[tid - 1] : 0;
    for (int i = 0; i < CH; ++i) {
        int idx = base + i;
        if (idx < NATOM) { rowptr[idx] = run; run += cnt[idx]; }
    }
    if (tid == 255) rowptr[NATOM] = partial[255];
}

__global__ void fill_csr(const int* __restrict__ widx, int* __restrict__ cursor,
                         int* __restrict__ eid) {
    int e = blockIdx.x * 256 + threadIdx.x;
    if (e >= NEDGE) return;
    int pos = atomicAdd(&cursor[widx[e]], 1);
    eid[pos] = e;
}

// ---------------- segmented sum+max, one wave per atom, no atomics ----------
// lane owns cols [lane*4,+4). H_b >= 0 (relu chain) so 0-init max is exact and
// empty segments give 0 (matches reference). amax stored bf16 (exact: max of
// bf16 values is a bf16).
template<int WITHMAX>
__global__ __launch_bounds__(256) void seg_reduce(
    const __bf16* __restrict__ Hb, const int* __restrict__ rowptr,
    const int* __restrict__ eid,
    float* __restrict__ asum, __bf16* __restrict__ amaxb)
{
    int a = blockIdx.x * 4 + (threadIdx.x >> 6);
    if (a >= NATOM) return;
    const int lane = threadIdx.x & 63;
    const int beg = rowptr[a], end = rowptr[a + 1];
    float s0 = 0.f, s1 = 0.f, s2 = 0.f, s3 = 0.f;
    float m0 = 0.f, m1 = 0.f, m2 = 0.f, m3 = 0.f;
    for (int i = beg; i < end; ++i) {
        int e = eid[i];
        bf16x4 h = *(const bf16x4*)(Hb + (size_t)e * DH + lane * 4);
        float v0 = (float)h[0], v1 = (float)h[1], v2 = (float)h[2], v3 = (float)h[3];
        s0 += v0; s1 += v1; s2 += v2; s3 += v3;
        if (WITHMAX) {
            m0 = fmaxf(m0, v0); m1 = fmaxf(m1, v1);
            m2 = fmaxf(m2, v2); m3 = fmaxf(m3, v3);
        }
    }
    size_t o = (size_t)a * DH + lane * 4;
    *(f32x4*)(asum + o) = (f32x4){s0, s1, s2, s3};
    if (WITHMAX) {
        bf16x4 mv; mv[0] = (__bf16)m0; mv[1] = (__bf16)m1; mv[2] = (__bf16)m2; mv[3] = (__bf16)m3;
        *(bf16x4*)(amaxb + o) = mv;
    }
}

// ---------------- weight pad/convert: dst[256,KD] <- f32 src[256 rows, srcld] --
__global__ void pad_w2(const float* __restrict__ src, __bf16* __restrict__ dst,
                       int srcld, int coloff, int KS, int KD) {
    int i = blockIdx.x * 256 + threadIdx.x;
    if (i >= 256 * KD) return;
    int n = i / KD, c = i - n * KD;
    dst[i] = (c < KS) ? (__bf16)src[(size_t)n * srcld + coloff + c] : (__bf16)0.f;
}

// ---------------- launcher ----------------
static inline int cdiv(long a, long b) { return (int)((a + b - 1) / b); }
static inline int gsz(int nch) { return nch < 512 ? nch : 512; }

extern "C" void kernel_launch(void* const* d_in, const int* in_sizes, int n_in,
                              void* d_out, int out_size, void* d_ws, size_t ws_size,
                              hipStream_t stream) {
    const float* V    = (const float*)d_in[0];
    const float* Ef   = (const float*)d_in[1];
    const int*   ei   = (const int*)d_in[2];      // [0:E)=v, [E:2E)=w
    const int*   rev  = (const int*)d_in[3];
    const float* Wi_a = (const float*)d_in[4];    // [256,133]
    const float* Wi_b = (const float*)d_in[5];    // [256,147]
    const float* Wh_a = (const float*)d_in[6];    // [256,256]
    const float* Wh_b = (const float*)d_in[7];
    const float* Wf_a = (const float*)d_in[8];
    const float* Wf_b = (const float*)d_in[9];
    const float* Wo   = (const float*)d_in[10];   // [256,389]
    float* out = (float*)d_out;

    const int* vidx = ei;
    const int* widx = ei + NEDGE;

    // ---- workspace layout (~245.3 MB, same footprint that passed R3/R4) ----
    // Hb @0 (102.4M) | Ha @102.4M (25.6M) | S @128M (64M) | asum @192M (51.2M)
    // | weights @243.2M (0.9M) | CSR -> ends 245,301,504
    // S lifetimes: iter: amaxb [0:25.6M) + Ta [25.6:51.2M) -> Tb [0:51.2M)
    //              readout: T [25.6:51.2M)
    char* ws = (char*)d_ws;
    __bf16* Hb    = (__bf16*)(ws + 0);
    __bf16* Ha    = (__bf16*)(ws + 102400000);
    char*   S     = ws + 128000000;
    float*  asum  = (float*)(ws + 192000000);
    __bf16* amaxb = (__bf16*)(S + 0);
    __bf16* Ta    = (__bf16*)(S + 25600000);      // 50000*256*2 = 25.6M
    __bf16* Tb    = (__bf16*)(S + 0);             // 100000*256*2 = 51.2M
    __bf16* T     = (__bf16*)(S + 25600000);      // readout tmp, 25.6M
    __bf16* Wia   = (__bf16*)(ws + 243200000);    // 81,920
    __bf16* Wib   = (__bf16*)(ws + 243281920);    // 81,920
    __bf16* Wo1   = (__bf16*)(ws + 243363840);    // 81,920
    __bf16* Wo2   = (__bf16*)(ws + 243445760);    // 131,072
    __bf16* Wha   = (__bf16*)(ws + 243576832);    // 131,072
    __bf16* Whb   = (__bf16*)(ws + 243707904);    // 131,072
    __bf16* Wfa   = (__bf16*)(ws + 243838976);    // 131,072
    __bf16* Wfb   = (__bf16*)(ws + 243970048);    // 131,072 -> 244,101,120
    int*  rowptr  = (int*)(ws + 244101120);
    int*  cursor  = (int*)(ws + 244301312);
    int*  eid     = (int*)(ws + 244501504);       // ends 245,301,504
    (void)ws_size;

    // ---- CSR build ----
    hipMemsetAsync(cursor, 0, NATOM * sizeof(int), stream);
    count_deg<<<cdiv(NEDGE, 256), 256, 0, stream>>>(widx, cursor);
    scan_counts<<<1, 256, 0, stream>>>(cursor, rowptr);
    hipMemcpyAsync(cursor, rowptr, NATOM * sizeof(int), hipMemcpyDeviceToDevice, stream);
    fill_csr<<<cdiv(NEDGE, 256), 256, 0, stream>>>(widx, cursor, eid);

    // ---- weights -> bf16 (padded) ----
    pad_w2<<<cdiv(256 * KVP, 256), 256, 0, stream>>>(Wi_a, Wia, DV, 0, DV, KVP);
    pad_w2<<<cdiv(256 * KVP, 256), 256, 0, stream>>>(Wi_b, Wib, DV + DE, 0, DV + DE, KVP);
    pad_w2<<<cdiv(256 * KVP, 256), 256, 0, stream>>>(Wo, Wo1, DV + DH, 0, DV, KVP);
    pad_w2<<<cdiv(256 * DH, 256), 256, 0, stream>>>(Wo, Wo2, DV + DH, DV, DH, DH);
    pad_w2<<<cdiv(256 * DH, 256), 256, 0, stream>>>(Wh_a, Wha, DH, 0, DH, DH);
    pad_w2<<<cdiv(256 * DH, 256), 256, 0, stream>>>(Wh_b, Whb, DH, 0, DH, DH);
    pad_w2<<<cdiv(256 * DH, 256), 256, 0, stream>>>(Wf_a, Wfa, DH, 0, DH, DH);
    pad_w2<<<cdiv(256 * DH, 256), 256, 0, stream>>>(Wf_b, Wfb, DH, 0, DH, DH);

    GArgs ga{};
    ga.asum = asum; ga.amaxb = amaxb; ga.HbG = Hb; ga.vidx = vidx; ga.rev = rev;
    ga.Vf = V; ga.Ef = Ef;

    // ---- input GEMMs: H_a = relu(V @ Wi_a^T), H_b = relu([V[v]|Ef] @ Wi_b^T) ----
    {
        int nch = cdiv(NATOM, 64);
        ga.W = Wia; ga.ldw = KVP; ga.C = Ha;
        ga.Mloc = NATOM; ga.part0 = NATOM; ga.off0 = 0; ga.off1 = 0;
        gemm_bs<AM_VF32, EPI_RELU, 0, 0, 5><<<gsz(nch), 256, 0, stream>>>(ga, nch);
    }
    {
        int nch = cdiv(NEDGE, 64);
        ga.W = Wib; ga.ldw = KVP; ga.C = Hb;
        ga.Mloc = NEDGE; ga.part0 = NEDGE; ga.off0 = 0; ga.off1 = 0;
        gemm_bs<AM_XB, EPI_RELU, 0, 0, 5><<<gsz(nch), 256, 0, stream>>>(ga, nch);
    }

    // ---- message passing iterations ----
    for (int it = 0; it < 2; ++it) {
        seg_reduce<1><<<cdiv(NATOM, 4), 256, 0, stream>>>(Hb, rowptr, eid, asum, amaxb);

        // atoms: Ta = Ha + bf16(asum*amax) @ Wh_a^T ; Ha += relu(Ta @ Wf_a^T)
        {
            int nch = cdiv(NATOM, 64);
            ga.W = Wha; ga.ldw = DH; ga.base = Ha; ga.C = Ta;
            ga.Mloc = NATOM; ga.part0 = NATOM; ga.off0 = 0; ga.off1 = 0;
            gemm_bs<AM_GATE, EPI_ADDBASE, 1, 0, 8><<<gsz(nch), 256, 0, stream>>>(ga, nch);
            ga.A = Ta; ga.lda = DH; ga.W = Wfa; ga.base = Ha; ga.C = Ha;
            gemm_bs<AM_PLAIN, EPI_FUSE, 0, 0, 8><<<gsz(nch), 256, 0, stream>>>(ga, nch);
        }

        // bonds, 2 pair-closed chunks (rows [c*50K,+50K) U [100K+c*50K,+50K)):
        //   Tb = Hb + bf16(asum[v]-Hb[rev]) @ Wh_b^T ; Hb += relu(Tb @ Wf_b^T).
        // rev maps within each chunk, so later chunks never read updated rows.
        for (int c = 0; c < 2; ++c) {
            int nch = cdiv(HALF, 64);
            ga.W = Whb; ga.ldw = DH; ga.base = Hb; ga.C = Tb;
            ga.Mloc = HALF; ga.part0 = HALF / 2; ga.off0 = c * 50000; ga.off1 = HALF + c * 50000;
            gemm_bs<AM_GDIFF, EPI_ADDBASE, 1, 0, 8><<<gsz(nch), 256, 0, stream>>>(ga, nch);
            ga.A = Tb; ga.lda = DH; ga.W = Wfb; ga.base = Hb; ga.C = Hb;
            gemm_bs<AM_PLAIN, EPI_FUSE, 0, 0, 8><<<gsz(nch), 256, 0, stream>>>(ga, nch);
        }
    }

    // ---- readout: out = relu(V @ Wo1^T + a_sum @ Wo2^T) ----
    seg_reduce<0><<<cdiv(NATOM, 4), 256, 0, stream>>>(Hb, rowptr, eid, asum, nullptr);
    {
        int nch = cdiv(NATOM, 64);
        ga.Mloc = NATOM; ga.part0 = NATOM; ga.off0 = 0; ga.off1 = 0;
        ga.W = Wo1; ga.ldw = KVP; ga.C = T;
        gemm_bs<AM_VF32, EPI_NONE, 0, 0, 5><<<gsz(nch), 256, 0, stream>>>(ga, nch);
        ga.W = Wo2; ga.ldw = DH; ga.base = T; ga.Cf = out;
        gemm_bs<AM_F32, EPI_RELUADD, 0, 1, 8><<<gsz(nch), 256, 0, stream>>>(ga, nch);
    }
}

// Round 6
// 1407.154 us; speedup vs baseline: 3.8900x; 1.3012x over previous
//
#include <hip/hip_runtime.h>
#include <hip/hip_bf16.h>

// ---------------- problem constants (fixed by reference) ----------------
#define NATOM 50000
#define NEDGE 200000
#define HALF  100000
#define DV    133
#define DE    14
#define DH    256
#define KVP   160   // pad 133/147 -> 160 (5 k-steps)

typedef __bf16  bf16x8 __attribute__((ext_vector_type(8)));
typedef __bf16  bf16x4 __attribute__((ext_vector_type(4)));
typedef float   f32x4  __attribute__((ext_vector_type(4)));

enum { EPI_RELU = 0, EPI_ADDBASE = 1, EPI_FUSE = 2, EPI_NONE = 3, EPI_RELUADD = 4 };
enum { AM_PLAIN = 0, AM_GATE = 1, AM_GDIFF = 2, AM_VF32 = 3, AM_XB = 4, AM_F32 = 5 };

// ---------------- LDS-staged, B-stationary MFMA GEMM ----------------
// C[rows,256] = epi(A'[rows,K] @ W[256,K]^T).  Block = 4 waves; wave wv owns
// cols [wv*64,+64) holding its W slice in registers (4 x KSTEPS frags).
// Per 64-row chunk: 256 threads cooperatively synthesize the A-panel
// (fused per AMODE) into LDS with batched wide loads, barrier, then all
// waves ds_read_b128 their a-frags (padded stride: uniform bank spread).
// Row map: local gr -> global (gr < part0 ? off0+gr : off1+gr-part0).
// A' synthesis: PLAIN bf16 A[local]; GATE bf16(asum*amax); GDIFF
// bf16(asum[vidx]-Hb[rev]); VF32 bf16(V) w<133; XB [V[vidx]|Ef] w<147; F32 bf16(asum).
struct GArgs {
    const __bf16* A; int lda;
    const float* asum; const __bf16* amaxb;
    const __bf16* HbG; const int* vidx; const int* rev;
    const float* Vf; const float* Ef;
    const __bf16* W; int ldw;
    const __bf16* base; __bf16* C; float* Cf;
    int Mloc; int part0; int off0; int off1;
};

template<int AMODE, int EPI, int CLOC, int STF32, int KSTEPS>
__global__ __launch_bounds__(256, 2) void gemm_ls(GArgs g, int nch) {
    constexpr int LSTR = KSTEPS * 32 + 8;    // bf16 elems/row; +8 pad => 4-bank row shift
    __shared__ __bf16 lds[64 * LSTR];
    const int lane = threadIdx.x & 63;
    const int wv   = threadIdx.x >> 6;
    const int quad = lane >> 4;
    const int l16  = lane & 15;
    const int colb = wv * 64;
    const int tr   = threadIdx.x >> 2;       // staging: row in chunk (0..63)
    const int tq   = threadIdx.x & 3;        // staging: col quarter

    // ---- stationary B slice (one-time, L2) ----
    bf16x8 bfr[4 * KSTEPS];
    {
        const __bf16* Wp = g.W + (size_t)(colb + l16) * g.ldw + quad * 8;
#pragma unroll
        for (int n = 0; n < 4; ++n)
#pragma unroll
            for (int k = 0; k < KSTEPS; ++k)
                bfr[n * KSTEPS + k] = *(const bf16x8*)(Wp + (size_t)(n * 16) * g.ldw + k * 32);
    }

    for (int ch = blockIdx.x; ch < nch; ch += gridDim.x) {
        const int gr0 = ch * 64;

        // ---- stage A panel into LDS (fused synthesis, batched loads) ----
        {
            int gr = gr0 + tr; if (gr > g.Mloc - 1) gr = g.Mloc - 1;
            const int map = (gr < g.part0) ? g.off0 + gr : g.off1 + gr - g.part0;
            __bf16* dst = lds + tr * LSTR;
            if (AMODE == AM_PLAIN) {
                const __bf16* Ap = g.A + (size_t)gr * g.lda;
#pragma unroll
                for (int kk = 0; kk < KSTEPS; ++kk) {
                    int c0 = kk * 32 + tq * 8;
                    *(bf16x8*)(dst + c0) = *(const bf16x8*)(Ap + c0);
                }
            } else if (AMODE == AM_GATE) {
                const float*  sp = g.asum  + (size_t)map * DH;
                const __bf16* mp = g.amaxb + (size_t)map * DH;
#pragma unroll
                for (int kk = 0; kk < KSTEPS; ++kk) {
                    int c0 = kk * 32 + tq * 8;
                    f32x4 s0 = *(const f32x4*)(sp + c0), s1 = *(const f32x4*)(sp + c0 + 4);
                    bf16x8 mx = *(const bf16x8*)(mp + c0);
                    bf16x8 v;
#pragma unroll
                    for (int j = 0; j < 4; ++j) {
                        v[j]     = (__bf16)(s0[j] * (float)mx[j]);
                        v[4 + j] = (__bf16)(s1[j] * (float)mx[4 + j]);
                    }
                    *(bf16x8*)(dst + c0) = v;
                }
            } else if (AMODE == AM_GDIFF) {
                const float*  sp = g.asum + (size_t)g.vidx[map] * DH;
                const __bf16* hp = g.HbG  + (size_t)g.rev[map]  * DH;
#pragma unroll
                for (int kk = 0; kk < KSTEPS; ++kk) {
                    int c0 = kk * 32 + tq * 8;
                    f32x4 s0 = *(const f32x4*)(sp + c0), s1 = *(const f32x4*)(sp + c0 + 4);
                    bf16x8 h = *(const bf16x8*)(hp + c0);
                    bf16x8 v;
#pragma unroll
                    for (int j = 0; j < 4; ++j) {
                        v[j]     = (__bf16)(s0[j] - (float)h[j]);
                        v[4 + j] = (__bf16)(s1[j] - (float)h[4 + j]);
                    }
                    *(bf16x8*)(dst + c0) = v;
                }
            } else if (AMODE == AM_F32) {
                const float* sp = g.asum + (size_t)map * DH;
#pragma unroll
                for (int kk = 0; kk < KSTEPS; ++kk) {
                    int c0 = kk * 32 + tq * 8;
                    f32x4 s0 = *(const f32x4*)(sp + c0), s1 = *(const f32x4*)(sp + c0 + 4);
                    bf16x8 v;
#pragma unroll
                    for (int j = 0; j < 4; ++j) {
                        v[j]     = (__bf16)s0[j];
                        v[4 + j] = (__bf16)s1[j];
                    }
                    *(bf16x8*)(dst + c0) = v;
                }
            } else { // AM_VF32 / AM_XB
                const float* vp = (AMODE == AM_XB) ? g.Vf + (size_t)g.vidx[map] * DV
                                                   : g.Vf + (size_t)map * DV;
                const float* ep = (AMODE == AM_XB) ? g.Ef + (size_t)map * DE : nullptr;
#pragma unroll
                for (int kk = 0; kk < KSTEPS; ++kk) {
                    int c0 = kk * 32 + tq * 8;
                    bf16x8 v;
#pragma unroll
                    for (int t = 0; t < 8; ++t) {
                        int c = c0 + t;
                        float x = 0.f;
                        if (c < DV)                             x = vp[c];
                        else if (AMODE == AM_XB && c < DV + DE) x = ep[c - DV];
                        v[t] = (__bf16)x;
                    }
                    *(bf16x8*)(dst + c0) = v;
                }
            }
        }
        __syncthreads();

        // ---- compute: wave's 64x64 patch from LDS x stationary B ----
        f32x4 acc[16];
#pragma unroll
        for (int i = 0; i < 16; ++i) acc[i] = (f32x4){0.f, 0.f, 0.f, 0.f};
#pragma unroll
        for (int m = 0; m < 4; ++m) {
#pragma unroll
            for (int k = 0; k < KSTEPS; ++k) {
                bf16x8 af = *(const bf16x8*)(lds + (m * 16 + l16) * LSTR + k * 32 + quad * 8);
#pragma unroll
                for (int n = 0; n < 4; ++n)
                    acc[m * 4 + n] = __builtin_amdgcn_mfma_f32_16x16x32_bf16(
                        af, bfr[n * KSTEPS + k], acc[m * 4 + n], 0, 0, 0);
            }
        }

        // ---- epilogue ----
#pragma unroll
        for (int m = 0; m < 4; ++m)
#pragma unroll
        for (int n = 0; n < 4; ++n)
#pragma unroll
        for (int r = 0; r < 4; ++r) {
            int gr = gr0 + m * 16 + quad * 4 + r;
            if (gr < g.Mloc) {
                int mapped = (gr < g.part0) ? g.off0 + gr : g.off1 + gr - g.part0;
                int crow = CLOC ? gr : mapped;
                int col = colb + n * 16 + l16;
                size_t co = (size_t)crow * DH + col;
                float v = acc[m * 4 + n][r];
                float res;
                if (EPI == EPI_RELU)       res = v > 0.f ? v : 0.f;
                else if (EPI == EPI_NONE)  res = v;
                else {
                    float b = (float)g.base[(size_t)mapped * DH + col];
                    if (EPI == EPI_ADDBASE)      res = b + v;
                    else if (EPI == EPI_FUSE)    res = b + (v > 0.f ? v : 0.f);
                    else /* EPI_RELUADD */       { res = b + v; res = res > 0.f ? res : 0.f; }
                }
                if (STF32) g.Cf[co] = res;
                else       g.C[co]  = (__bf16)res;
            }
        }
        __syncthreads();   // LDS safe to overwrite next chunk
    }
}

// ---------------- CSR build (once per launch; widx constant) ----------------
__global__ void count_deg(const int* __restrict__ widx, int* __restrict__ cnt) {
    int e = blockIdx.x * 256 + threadIdx.x;
    if (e < NEDGE) atomicAdd(&cnt[widx[e]], 1);
}

__global__ __launch_bounds__(256) void scan_counts(const int* __restrict__ cnt,
                                                   int* __restrict__ rowptr) {
    __shared__ int partial[256];
    const int tid = threadIdx.x;
    const int CH = (NATOM + 255) / 256;
    const int base = tid * CH;
    int s = 0;
    for (int i = 0; i < CH; ++i) { int idx = base + i; if (idx < NATOM) s += cnt[idx]; }
    partial[tid] = s;
    __syncthreads();
    for (int off = 1; off < 256; off <<= 1) {
        int v = (tid >= off) ? partial[tid - off] : 0;
        __syncthreads();
        partial[tid] += v;
        __syncthreads();
    }
    int run = (tid > 0) ? partial[tid - 1] : 0;
    for (int i = 0; i < CH; ++i) {
        int idx = base + i;
        if (idx < NATOM) { rowptr[idx] = run; run += cnt[idx]; }
    }
    if (tid == 255) rowptr[NATOM] = partial[255];
}

__global__ void fill_csr(const int* __restrict__ widx, int* __restrict__ cursor,
                         int* __restrict__ eid) {
    int e = blockIdx.x * 256 + threadIdx.x;
    if (e >= NEDGE) return;
    int pos = atomicAdd(&cursor[widx[e]], 1);
    eid[pos] = e;
}

// ---------------- segmented sum+max, one wave per atom, no atomics ----------
// lane owns cols [lane*4,+4). H_b >= 0 (relu chain) so 0-init max is exact and
// empty segments give 0 (matches reference). amax stored bf16 (exact).
template<int WITHMAX>
__global__ __launch_bounds__(256) void seg_reduce(
    const __bf16* __restrict__ Hb, const int* __restrict__ rowptr,
    const int* __restrict__ eid,
    float* __restrict__ asum, __bf16* __restrict__ amaxb)
{
    int a = blockIdx.x * 4 + (threadIdx.x >> 6);
    if (a >= NATOM) return;
    const int lane = threadIdx.x & 63;
    const int beg = rowptr[a], end = rowptr[a + 1];
    float s0 = 0.f, s1 = 0.f, s2 = 0.f, s3 = 0.f;
    float m0 = 0.f, m1 = 0.f, m2 = 0.f, m3 = 0.f;
    for (int i = beg; i < end; ++i) {
        int e = eid[i];
        bf16x4 h = *(const bf16x4*)(Hb + (size_t)e * DH + lane * 4);
        float v0 = (float)h[0], v1 = (float)h[1], v2 = (float)h[2], v3 = (float)h[3];
        s0 += v0; s1 += v1; s2 += v2; s3 += v3;
        if (WITHMAX) {
            m0 = fmaxf(m0, v0); m1 = fmaxf(m1, v1);
            m2 = fmaxf(m2, v2); m3 = fmaxf(m3, v3);
        }
    }
    size_t o = (size_t)a * DH + lane * 4;
    *(f32x4*)(asum + o) = (f32x4){s0, s1, s2, s3};
    if (WITHMAX) {
        bf16x4 mv; mv[0] = (__bf16)m0; mv[1] = (__bf16)m1; mv[2] = (__bf16)m2; mv[3] = (__bf16)m3;
        *(bf16x4*)(amaxb + o) = mv;
    }
}

// ---------------- weight pad/convert: dst[256,KD] <- f32 src[256 rows, srcld] --
__global__ void pad_w2(const float* __restrict__ src, __bf16* __restrict__ dst,
                       int srcld, int coloff, int KS, int KD) {
    int i = blockIdx.x * 256 + threadIdx.x;
    if (i >= 256 * KD) return;
    int n = i / KD, c = i - n * KD;
    dst[i] = (c < KS) ? (__bf16)src[(size_t)n * srcld + coloff + c] : (__bf16)0.f;
}

// ---------------- launcher ----------------
static inline int cdiv(long a, long b) { return (int)((a + b - 1) / b); }
static inline int gsz(int nch) { return nch < 512 ? nch : 512; }

extern "C" void kernel_launch(void* const* d_in, const int* in_sizes, int n_in,
                              void* d_out, int out_size, void* d_ws, size_t ws_size,
                              hipStream_t stream) {
    const float* V    = (const float*)d_in[0];
    const float* Ef   = (const float*)d_in[1];
    const int*   ei   = (const int*)d_in[2];      // [0:E)=v, [E:2E)=w
    const int*   rev  = (const int*)d_in[3];
    const float* Wi_a = (const float*)d_in[4];
    const float* Wi_b = (const float*)d_in[5];
    const float* Wh_a = (const float*)d_in[6];
    const float* Wh_b = (const float*)d_in[7];
    const float* Wf_a = (const float*)d_in[8];
    const float* Wf_b = (const float*)d_in[9];
    const float* Wo   = (const float*)d_in[10];
    float* out = (float*)d_out;

    const int* vidx = ei;
    const int* widx = ei + NEDGE;

    // ---- workspace layout (~245.3 MB, unchanged from R4/R5) ----
    char* ws = (char*)d_ws;
    __bf16* Hb    = (__bf16*)(ws + 0);
    __bf16* Ha    = (__bf16*)(ws + 102400000);
    char*   S     = ws + 128000000;
    float*  asum  = (float*)(ws + 192000000);
    __bf16* amaxb = (__bf16*)(S + 0);
    __bf16* Ta    = (__bf16*)(S + 25600000);
    __bf16* Tb    = (__bf16*)(S + 0);
    __bf16* T     = (__bf16*)(S + 25600000);
    __bf16* Wia   = (__bf16*)(ws + 243200000);
    __bf16* Wib   = (__bf16*)(ws + 243281920);
    __bf16* Wo1   = (__bf16*)(ws + 243363840);
    __bf16* Wo2   = (__bf16*)(ws + 243445760);
    __bf16* Wha   = (__bf16*)(ws + 243576832);
    __bf16* Whb   = (__bf16*)(ws + 243707904);
    __bf16* Wfa   = (__bf16*)(ws + 243838976);
    __bf16* Wfb   = (__bf16*)(ws + 243970048);
    int*  rowptr  = (int*)(ws + 244101120);
    int*  cursor  = (int*)(ws + 244301312);
    int*  eid     = (int*)(ws + 244501504);
    (void)ws_size;

    // ---- CSR build ----
    hipMemsetAsync(cursor, 0, NATOM * sizeof(int), stream);
    count_deg<<<cdiv(NEDGE, 256), 256, 0, stream>>>(widx, cursor);
    scan_counts<<<1, 256, 0, stream>>>(cursor, rowptr);
    hipMemcpyAsync(cursor, rowptr, NATOM * sizeof(int), hipMemcpyDeviceToDevice, stream);
    fill_csr<<<cdiv(NEDGE, 256), 256, 0, stream>>>(widx, cursor, eid);

    // ---- weights -> bf16 (padded) ----
    pad_w2<<<cdiv(256 * KVP, 256), 256, 0, stream>>>(Wi_a, Wia, DV, 0, DV, KVP);
    pad_w2<<<cdiv(256 * KVP, 256), 256, 0, stream>>>(Wi_b, Wib, DV + DE, 0, DV + DE, KVP);
    pad_w2<<<cdiv(256 * KVP, 256), 256, 0, stream>>>(Wo, Wo1, DV + DH, 0, DV, KVP);
    pad_w2<<<cdiv(256 * DH, 256), 256, 0, stream>>>(Wo, Wo2, DV + DH, DV, DH, DH);
    pad_w2<<<cdiv(256 * DH, 256), 256, 0, stream>>>(Wh_a, Wha, DH, 0, DH, DH);
    pad_w2<<<cdiv(256 * DH, 256), 256, 0, stream>>>(Wh_b, Whb, DH, 0, DH, DH);
    pad_w2<<<cdiv(256 * DH, 256), 256, 0, stream>>>(Wf_a, Wfa, DH, 0, DH, DH);
    pad_w2<<<cdiv(256 * DH, 256), 256, 0, stream>>>(Wf_b, Wfb, DH, 0, DH, DH);

    GArgs ga{};
    ga.asum = asum; ga.amaxb = amaxb; ga.HbG = Hb; ga.vidx = vidx; ga.rev = rev;
    ga.Vf = V; ga.Ef = Ef;

    // ---- input GEMMs ----
    {
        int nch = cdiv(NATOM, 64);
        ga.W = Wia; ga.ldw = KVP; ga.C = Ha;
        ga.Mloc = NATOM; ga.part0 = NATOM; ga.off0 = 0; ga.off1 = 0;
        gemm_ls<AM_VF32, EPI_RELU, 0, 0, 5><<<gsz(nch), 256, 0, stream>>>(ga, nch);
    }
    {
        int nch = cdiv(NEDGE, 64);
        ga.W = Wib; ga.ldw = KVP; ga.C = Hb;
        ga.Mloc = NEDGE; ga.part0 = NEDGE; ga.off0 = 0; ga.off1 = 0;
        gemm_ls<AM_XB, EPI_RELU, 0, 0, 5><<<gsz(nch), 256, 0, stream>>>(ga, nch);
    }

    // ---- message passing iterations ----
    for (int it = 0; it < 2; ++it) {
        seg_reduce<1><<<cdiv(NATOM, 4), 256, 0, stream>>>(Hb, rowptr, eid, asum, amaxb);

        // atoms: Ta = Ha + bf16(asum*amax) @ Wh_a^T ; Ha += relu(Ta @ Wf_a^T)
        {
            int nch = cdiv(NATOM, 64);
            ga.W = Wha; ga.ldw = DH; ga.base = Ha; ga.C = Ta;
            ga.Mloc = NATOM; ga.part0 = NATOM; ga.off0 = 0; ga.off1 = 0;
            gemm_ls<AM_GATE, EPI_ADDBASE, 1, 0, 8><<<gsz(nch), 256, 0, stream>>>(ga, nch);
            ga.A = Ta; ga.lda = DH; ga.W = Wfa; ga.base = Ha; ga.C = Ha;
            gemm_ls<AM_PLAIN, EPI_FUSE, 0, 0, 8><<<gsz(nch), 256, 0, stream>>>(ga, nch);
        }

        // bonds, 2 pair-closed chunks (rows [c*50K,+50K) U [100K+c*50K,+50K)):
        //   Tb = Hb + bf16(asum[v]-Hb[rev]) @ Wh_b^T ; Hb += relu(Tb @ Wf_b^T).
        // rev maps within each chunk, so later chunks never read updated rows.
        for (int c = 0; c < 2; ++c) {
            int nch = cdiv(HALF, 64);
            ga.W = Whb; ga.ldw = DH; ga.base = Hb; ga.C = Tb;
            ga.Mloc = HALF; ga.part0 = HALF / 2; ga.off0 = c * 50000; ga.off1 = HALF + c * 50000;
            gemm_ls<AM_GDIFF, EPI_ADDBASE, 1, 0, 8><<<gsz(nch), 256, 0, stream>>>(ga, nch);
            ga.A = Tb; ga.lda = DH; ga.W = Wfb; ga.base = Hb; ga.C = Hb;
            gemm_ls<AM_PLAIN, EPI_FUSE, 0, 0, 8><<<gsz(nch), 256, 0, stream>>>(ga, nch);
        }
    }

    // ---- readout: out = relu(V @ Wo1^T + a_sum @ Wo2^T) ----
    seg_reduce<0><<<cdiv(NATOM, 4), 256, 0, stream>>>(Hb, rowptr, eid, asum, nullptr);
    {
        int nch = cdiv(NATOM, 64);
        ga.Mloc = NATOM; ga.part0 = NATOM; ga.off0 = 0; ga.off1 = 0;
        ga.W = Wo1; ga.ldw = KVP; ga.C = T;
        gemm_ls<AM_VF32, EPI_NONE, 0, 0, 5><<<gsz(nch), 256, 0, stream>>>(ga, nch);
        ga.W = Wo2; ga.ldw = DH; ga.base = T; ga.Cf = out;
        gemm_ls<AM_F32, EPI_RELUADD, 0, 1, 8><<<gsz(nch), 256, 0, stream>>>(ga, nch);
    }
}

// Round 8
// 1267.860 us; speedup vs baseline: 4.3174x; 1.1099x over previous
//
#include <hip/hip_runtime.h>
#include <hip/hip_bf16.h>

// ---------------- problem constants (fixed by reference) ----------------
#define NATOM 50000
#define NEDGE 200000
#define HALF  100000
#define DV    133
#define DE    14
#define DH    256
#define KVP   160   // pad 133/147 -> 160 (5 K-iters of 32)

typedef __bf16  bf16x8 __attribute__((ext_vector_type(8)));
typedef __bf16  bf16x4 __attribute__((ext_vector_type(4)));
typedef float   f32x4  __attribute__((ext_vector_type(4)));

enum { EPI_RELU = 0, EPI_ADDBASE = 1, EPI_FUSE = 2, EPI_NONE = 3, EPI_RELUADD = 4 };
enum { AM_PLAIN = 0, AM_GATE = 1, AM_GDIFF = 2, AM_VF32 = 3, AM_XB = 4, AM_F32 = 5 };

// async global->LDS, 16B per lane; LDS dest = uniform base + lane*16
__device__ __forceinline__ void gll16(const void* g, void* l) {
    __builtin_amdgcn_global_load_lds(
        (const __attribute__((address_space(1))) unsigned int*)g,
        (__attribute__((address_space(3))) unsigned int*)l, 16, 0, 0);
}
// full drain (vmcnt=0, lgkmcnt=0) BEFORE barrier: guarantees global_load_lds
// and ds_write data is LDS-resident before any wave crosses. Defensive: the
// R7 post-timing divergence is consistent with a missing vmcnt drain on the
// mixed ds_write+gll staging paths.
__device__ __forceinline__ void drain_barrier() {
    __builtin_amdgcn_s_waitcnt(0);
    __syncthreads();
}

// ---------------- m97-style tiled GEMM: C[rows,256] = epi(A' @ W[256,K]^T) ----
// BM=128, BN=128 (blk&1 selects col half), BK=32, 256 thr / 4 waves (2x2 of
// 64x64, acc=16 f32x4). Per K-iter: B staged by global_load_lds (16B lanes);
// A staged by global_load_lds (PLAIN) or fused per-thread synthesis+ds_write
// (GATE/GDIFF/VF32/XB/F32). LDS tiles row-major [128][32], no padding.
// Row map: local gr -> global (gr < part0 ? off0+gr : off1+gr-part0).
struct GArgs {
    const __bf16* A; int lda;
    const float* asumf; const __bf16* amaxb;
    const __bf16* HbG; const int* vidx; const int* rev;
    const float* Vf; const float* Ef;
    const __bf16* W; int ldw;
    const __bf16* base; __bf16* C; float* Cf;
    int Mloc; int part0; int off0; int off1;
};

template<int AMODE, int EPI, int CLOC, int STF32, int KITERS>
__global__ __launch_bounds__(256, 2) void gemm128(GArgs g, int nblk) {
    __shared__ __bf16 Alds[4096];   // [128 rows][32 k]
    __shared__ __bf16 Blds[4096];   // [128 cols][32 k]
    const int tid  = threadIdx.x;
    const int lane = tid & 63, wv = tid >> 6;
    const int quad = lane >> 4, l16 = lane & 15;
    const int wr = (wv >> 1) * 64, wc = (wv & 1) * 64;
    const int lrow = lane >> 2, lu = lane & 3;   // gll: 16 rows x 4x16B units/call

    for (int blk = blockIdx.x; blk < nblk; blk += gridDim.x) {
        const int ch = blk >> 1, half = blk & 1;
        const int gr0  = ch * 128;
        const int colb = half * 128;

        // synth modes: thread stages row rs, 16-elem segment seg
        const int rs = tid >> 1, seg = tid & 1;
        const float *sp = nullptr; const __bf16 *hp = nullptr, *mp = nullptr;
        const float *vp = nullptr, *ep = nullptr;
        if (AMODE != AM_PLAIN) {
            int grs = gr0 + rs; if (grs > g.Mloc - 1) grs = g.Mloc - 1;
            const int maps = (grs < g.part0) ? g.off0 + grs : g.off1 + grs - g.part0;
            if (AMODE == AM_GATE)  { sp = g.asumf + (size_t)maps * DH; mp = g.amaxb + (size_t)maps * DH; }
            if (AMODE == AM_GDIFF) { sp = g.asumf + (size_t)g.vidx[maps] * DH; hp = g.HbG + (size_t)g.rev[maps] * DH; }
            if (AMODE == AM_F32)   { sp = g.asumf + (size_t)maps * DH; }
            if (AMODE == AM_VF32)  { vp = g.Vf + (size_t)maps * DV; }
            if (AMODE == AM_XB)    { vp = g.Vf + (size_t)g.vidx[maps] * DV; ep = g.Ef + (size_t)maps * DE; }
        }

        f32x4 acc[16];
#pragma unroll
        for (int i = 0; i < 16; ++i) acc[i] = (f32x4){0.f, 0.f, 0.f, 0.f};

        for (int kk = 0; kk < KITERS; ++kk) {
            // ---- stage B: 8KB, 2 gll calls per wave ----
#pragma unroll
            for (int s = 0; s < 2; ++s) {
                int cl = (wv * 2 + s) * 16 + lrow;
                gll16(g.W + (size_t)(colb + cl) * g.ldw + kk * 32 + lu * 8,
                      Blds + (wv * 2 + s) * 512);
            }
            // ---- stage A ----
            if (AMODE == AM_PLAIN) {
#pragma unroll
                for (int s = 0; s < 2; ++s) {
                    int r = (wv * 2 + s) * 16 + lrow;
                    int gra = gr0 + r; if (gra > g.Mloc - 1) gra = g.Mloc - 1;
                    gll16(g.A + (size_t)gra * g.lda + kk * 32 + lu * 8,
                          Alds + (wv * 2 + s) * 512);
                }
            } else {
                bf16x8 o0, o1;
                const int cb = kk * 32 + seg * 16;
                if (AMODE == AM_GATE || AMODE == AM_GDIFF || AMODE == AM_F32) {
                    f32x4 s0 = *(const f32x4*)(sp + cb);
                    f32x4 s1 = *(const f32x4*)(sp + cb + 4);
                    f32x4 s2 = *(const f32x4*)(sp + cb + 8);
                    f32x4 s3 = *(const f32x4*)(sp + cb + 12);
                    if (AMODE == AM_GATE) {
                        bf16x8 m0 = *(const bf16x8*)(mp + cb);
                        bf16x8 m1 = *(const bf16x8*)(mp + cb + 8);
#pragma unroll
                        for (int j = 0; j < 4; ++j) {
                            o0[j]     = (__bf16)(s0[j] * (float)m0[j]);
                            o0[4 + j] = (__bf16)(s1[j] * (float)m0[4 + j]);
                            o1[j]     = (__bf16)(s2[j] * (float)m1[j]);
                            o1[4 + j] = (__bf16)(s3[j] * (float)m1[4 + j]);
                        }
                    } else if (AMODE == AM_GDIFF) {
                        bf16x8 h0 = *(const bf16x8*)(hp + cb);
                        bf16x8 h1 = *(const bf16x8*)(hp + cb + 8);
#pragma unroll
                        for (int j = 0; j < 4; ++j) {
                            o0[j]     = (__bf16)(s0[j] - (float)h0[j]);
                            o0[4 + j] = (__bf16)(s1[j] - (float)h0[4 + j]);
                            o1[j]     = (__bf16)(s2[j] - (float)h1[j]);
                            o1[4 + j] = (__bf16)(s3[j] - (float)h1[4 + j]);
                        }
                    } else {
#pragma unroll
                        for (int j = 0; j < 4; ++j) {
                            o0[j]     = (__bf16)s0[j];
                            o0[4 + j] = (__bf16)s1[j];
                            o1[j]     = (__bf16)s2[j];
                            o1[4 + j] = (__bf16)s3[j];
                        }
                    }
                } else {   // AM_VF32 / AM_XB: f32 rows width 133(+14), K padded to 160
                    if (kk < 4) {            // cols <= 127: unguarded
                        f32x4 x0, x1, x2, x3;
                        __builtin_memcpy(&x0, vp + cb, 16);
                        __builtin_memcpy(&x1, vp + cb + 4, 16);
                        __builtin_memcpy(&x2, vp + cb + 8, 16);
                        __builtin_memcpy(&x3, vp + cb + 12, 16);
#pragma unroll
                        for (int j = 0; j < 4; ++j) {
                            o0[j] = (__bf16)x0[j]; o0[4 + j] = (__bf16)x1[j];
                            o1[j] = (__bf16)x2[j]; o1[4 + j] = (__bf16)x3[j];
                        }
                    } else {                 // boundary iter: per-element guard
#pragma unroll
                        for (int j = 0; j < 8; ++j) {
                            int c0 = cb + j, c1 = cb + 8 + j;
                            float y0 = 0.f, y1 = 0.f;
                            if (c0 < DV) y0 = vp[c0];
                            else if (AMODE == AM_XB && c0 < DV + DE) y0 = ep[c0 - DV];
                            if (c1 < DV) y1 = vp[c1];
                            else if (AMODE == AM_XB && c1 < DV + DE) y1 = ep[c1 - DV];
                            o0[j] = (__bf16)y0; o1[j] = (__bf16)y1;
                        }
                    }
                }
                *(bf16x8*)(Alds + rs * 32 + seg * 16)     = o0;
                *(bf16x8*)(Alds + rs * 32 + seg * 16 + 8) = o1;
            }
            drain_barrier();

            // ---- compute: 4 a-frags x 4 b-frags -> 16 MFMA ----
            bf16x8 af[4], bfv[4];
#pragma unroll
            for (int m = 0; m < 4; ++m)
                af[m] = *(const bf16x8*)(Alds + (wr + m * 16 + l16) * 32 + quad * 8);
#pragma unroll
            for (int n = 0; n < 4; ++n)
                bfv[n] = *(const bf16x8*)(Blds + (wc + n * 16 + l16) * 32 + quad * 8);
#pragma unroll
            for (int m = 0; m < 4; ++m)
#pragma unroll
                for (int n = 0; n < 4; ++n)
                    acc[m * 4 + n] = __builtin_amdgcn_mfma_f32_16x16x32_bf16(
                        af[m], bfv[n], acc[m * 4 + n], 0, 0, 0);
            drain_barrier();
        }

        // ---- epilogue: wave's 64x64 patch ----
#pragma unroll
        for (int m = 0; m < 4; ++m)
#pragma unroll
        for (int n = 0; n < 4; ++n)
#pragma unroll
        for (int r = 0; r < 4; ++r) {
            int gr = gr0 + wr + m * 16 + quad * 4 + r;
            if (gr < g.Mloc) {
                int mapped = (gr < g.part0) ? g.off0 + gr : g.off1 + gr - g.part0;
                int crow = CLOC ? gr : mapped;
                int col = colb + wc + n * 16 + l16;
                size_t co = (size_t)crow * DH + col;
                float v = acc[m * 4 + n][r];
                float res;
                if (EPI == EPI_RELU)       res = v > 0.f ? v : 0.f;
                else if (EPI == EPI_NONE)  res = v;
                else {
                    float b = (float)g.base[(size_t)mapped * DH + col];
                    if (EPI == EPI_ADDBASE)      res = b + v;
                    else if (EPI == EPI_FUSE)    res = b + (v > 0.f ? v : 0.f);
                    else /* EPI_RELUADD */       { res = b + v; res = res > 0.f ? res : 0.f; }
                }
                if (STF32) g.Cf[co] = res;
                else       g.C[co]  = (__bf16)res;
            }
        }
    }
}

// ---------------- CSR build (once per launch; widx constant) ----------------
__global__ void count_deg(const int* __restrict__ widx, int* __restrict__ cnt) {
    int e = blockIdx.x * 256 + threadIdx.x;
    if (e < NEDGE) atomicAdd(&cnt[widx[e]], 1);
}

__global__ __launch_bounds__(256) void scan_counts(const int* __restrict__ cnt,
                                                   int* __restrict__ rowptr) {
    __shared__ int partial[256];
    const int tid = threadIdx.x;
    const int CH = (NATOM + 255) / 256;
    const int base = tid * CH;
    int s = 0;
    for (int i = 0; i < CH; ++i) { int idx = base + i; if (idx < NATOM) s += cnt[idx]; }
    partial[tid] = s;
    __syncthreads();
    for (int off = 1; off < 256; off <<= 1) {
        int v = (tid >= off) ? partial[tid - off] : 0;
        __syncthreads();
        partial[tid] += v;
        __syncthreads();
    }
    int run = (tid > 0) ? partial[tid - 1] : 0;
    for (int i = 0; i < CH; ++i) {
        int idx = base + i;
        if (idx < NATOM) { rowptr[idx] = run; run += cnt[idx]; }
    }
    if (tid == 255) rowptr[NATOM] = partial[255];
}

__global__ void fill_csr(const int* __restrict__ widx, int* __restrict__ cursor,
                         int* __restrict__ eid) {
    int e = blockIdx.x * 256 + threadIdx.x;
    if (e >= NEDGE) return;
    int pos = atomicAdd(&cursor[widx[e]], 1);
    eid[pos] = e;
}

// ---------------- segmented sum+max, one wave per atom, no atomics ----------
// f32 sums (stored f32), bf16 max (exact: max of bf16 values is a bf16).
// H_b >= 0 (relu chain) so 0-init max is exact; empty segments -> 0 (ref rule).
template<int WITHMAX>
__global__ __launch_bounds__(256) void seg_reduce(
    const __bf16* __restrict__ Hb, const int* __restrict__ rowptr,
    const int* __restrict__ eid,
    float* __restrict__ asum, __bf16* __restrict__ amaxb)
{
    int a = blockIdx.x * 4 + (threadIdx.x >> 6);
    if (a >= NATOM) return;
    const int lane = threadIdx.x & 63;
    const int beg = rowptr[a], end = rowptr[a + 1];
    float s0 = 0.f, s1 = 0.f, s2 = 0.f, s3 = 0.f;
    float m0 = 0.f, m1 = 0.f, m2 = 0.f, m3 = 0.f;
    for (int i = beg; i < end; ++i) {
        int e = eid[i];
        bf16x4 h = *(const bf16x4*)(Hb + (size_t)e * DH + lane * 4);
        float v0 = (float)h[0], v1 = (float)h[1], v2 = (float)h[2], v3 = (float)h[3];
        s0 += v0; s1 += v1; s2 += v2; s3 += v3;
        if (WITHMAX) {
            m0 = fmaxf(m0, v0); m1 = fmaxf(m1, v1);
            m2 = fmaxf(m2, v2); m3 = fmaxf(m3, v3);
        }
    }
    size_t o = (size_t)a * DH + lane * 4;
    *(f32x4*)(asum + o) = (f32x4){s0, s1, s2, s3};
    if (WITHMAX) {
        bf16x4 mv; mv[0] = (__bf16)m0; mv[1] = (__bf16)m1; mv[2] = (__bf16)m2; mv[3] = (__bf16)m3;
        *(bf16x4*)(amaxb + o) = mv;
    }
}

// ---------------- weight pad/convert: dst[256,KD] <- f32 src[256 rows, srcld] --
__global__ void pad_w2(const float* __restrict__ src, __bf16* __restrict__ dst,
                       int srcld, int coloff, int KS, int KD) {
    int i = blockIdx.x * 256 + threadIdx.x;
    if (i >= 256 * KD) return;
    int n = i / KD, c = i - n * KD;
    dst[i] = (c < KS) ? (__bf16)src[(size_t)n * srcld + coloff + c] : (__bf16)0.f;
}

// ---------------- launcher ----------------
static inline int cdiv(long a, long b) { return (int)((a + b - 1) / b); }
static inline int gsz2(int nblk) { return nblk < 2048 ? nblk : 2048; }

extern "C" void kernel_launch(void* const* d_in, const int* in_sizes, int n_in,
                              void* d_out, int out_size, void* d_ws, size_t ws_size,
                              hipStream_t stream) {
    const float* V    = (const float*)d_in[0];
    const float* Ef   = (const float*)d_in[1];
    const int*   ei   = (const int*)d_in[2];      // [0:E)=v, [E:2E)=w
    const int*   rev  = (const int*)d_in[3];
    const float* Wi_a = (const float*)d_in[4];
    const float* Wi_b = (const float*)d_in[5];
    const float* Wh_a = (const float*)d_in[6];
    const float* Wh_b = (const float*)d_in[7];
    const float* Wf_a = (const float*)d_in[8];
    const float* Wf_b = (const float*)d_in[9];
    const float* Wo   = (const float*)d_in[10];
    float* out = (float*)d_out;

    const int* vidx = ei;
    const int* widx = ei + NEDGE;

    // ---- workspace layout (~245.3 MB, identical to the R6 passing layout) ----
    char* ws = (char*)d_ws;
    __bf16* Hb    = (__bf16*)(ws + 0);            // 102.4M
    __bf16* Ha    = (__bf16*)(ws + 102400000);    // 25.6M
    char*   S     = ws + 128000000;               // 64M scratch
    float*  asum  = (float*)(ws + 192000000);     // 51.2M (f32)
    __bf16* amaxb = (__bf16*)(S + 0);             // 25.6M (dead before Tb live)
    __bf16* Ta    = (__bf16*)(S + 25600000);      // 25.6M
    __bf16* Tb    = (__bf16*)(S + 0);             // 51.2M
    __bf16* T     = (__bf16*)(S + 25600000);      // readout tmp
    __bf16* Wia   = (__bf16*)(ws + 243200000);
    __bf16* Wib   = (__bf16*)(ws + 243281920);
    __bf16* Wo1   = (__bf16*)(ws + 243363840);
    __bf16* Wo2   = (__bf16*)(ws + 243445760);
    __bf16* Wha   = (__bf16*)(ws + 243576832);
    __bf16* Whb   = (__bf16*)(ws + 243707904);
    __bf16* Wfa   = (__bf16*)(ws + 243838976);
    __bf16* Wfb   = (__bf16*)(ws + 243970048);
    int*  rowptr  = (int*)(ws + 244101120);
    int*  cursor  = (int*)(ws + 244301312);
    int*  eid     = (int*)(ws + 244501504);
    (void)ws_size;

    // ---- CSR build ----
    hipMemsetAsync(cursor, 0, NATOM * sizeof(int), stream);
    count_deg<<<cdiv(NEDGE, 256), 256, 0, stream>>>(widx, cursor);
    scan_counts<<<1, 256, 0, stream>>>(cursor, rowptr);
    hipMemcpyAsync(cursor, rowptr, NATOM * sizeof(int), hipMemcpyDeviceToDevice, stream);
    fill_csr<<<cdiv(NEDGE, 256), 256, 0, stream>>>(widx, cursor, eid);

    // ---- weights -> bf16 (padded) ----
    pad_w2<<<cdiv(256 * KVP, 256), 256, 0, stream>>>(Wi_a, Wia, DV, 0, DV, KVP);
    pad_w2<<<cdiv(256 * KVP, 256), 256, 0, stream>>>(Wi_b, Wib, DV + DE, 0, DV + DE, KVP);
    pad_w2<<<cdiv(256 * KVP, 256), 256, 0, stream>>>(Wo, Wo1, DV + DH, 0, DV, KVP);
    pad_w2<<<cdiv(256 * DH, 256), 256, 0, stream>>>(Wo, Wo2, DV + DH, DV, DH, DH);
    pad_w2<<<cdiv(256 * DH, 256), 256, 0, stream>>>(Wh_a, Wha, DH, 0, DH, DH);
    pad_w2<<<cdiv(256 * DH, 256), 256, 0, stream>>>(Wh_b, Whb, DH, 0, DH, DH);
    pad_w2<<<cdiv(256 * DH, 256), 256, 0, stream>>>(Wf_a, Wfa, DH, 0, DH, DH);
    pad_w2<<<cdiv(256 * DH, 256), 256, 0, stream>>>(Wf_b, Wfb, DH, 0, DH, DH);

    GArgs ga{};
    ga.asumf = asum; ga.amaxb = amaxb; ga.HbG = Hb; ga.vidx = vidx; ga.rev = rev;
    ga.Vf = V; ga.Ef = Ef;

    // ---- input GEMMs: H_a = relu(V @ Wi_a^T), H_b = relu([V[v]|Ef] @ Wi_b^T) ----
    {
        int nblk = cdiv(NATOM, 128) * 2;
        ga.W = Wia; ga.ldw = KVP; ga.C = Ha;
        ga.Mloc = NATOM; ga.part0 = NATOM; ga.off0 = 0; ga.off1 = 0;
        gemm128<AM_VF32, EPI_RELU, 0, 0, 5><<<gsz2(nblk), 256, 0, stream>>>(ga, nblk);
    }
    {
        int nblk = cdiv(NEDGE, 128) * 2;
        ga.W = Wib; ga.ldw = KVP; ga.C = Hb;
        ga.Mloc = NEDGE; ga.part0 = NEDGE; ga.off0 = 0; ga.off1 = 0;
        gemm128<AM_XB, EPI_RELU, 0, 0, 5><<<gsz2(nblk), 256, 0, stream>>>(ga, nblk);
    }

    // ---- message passing iterations ----
    for (int it = 0; it < 2; ++it) {
        seg_reduce<1><<<cdiv(NATOM, 4), 256, 0, stream>>>(Hb, rowptr, eid, asum, amaxb);

        // atoms: Ta = Ha + bf16(asum*amax) @ Wh_a^T ; Ha += relu(Ta @ Wf_a^T)
        {
            int nblk = cdiv(NATOM, 128) * 2;
            ga.W = Wha; ga.ldw = DH; ga.base = Ha; ga.C = Ta;
            ga.Mloc = NATOM; ga.part0 = NATOM; ga.off0 = 0; ga.off1 = 0;
            gemm128<AM_GATE, EPI_ADDBASE, 1, 0, 8><<<gsz2(nblk), 256, 0, stream>>>(ga, nblk);
            ga.A = Ta; ga.lda = DH; ga.W = Wfa; ga.base = Ha; ga.C = Ha;
            gemm128<AM_PLAIN, EPI_FUSE, 0, 0, 8><<<gsz2(nblk), 256, 0, stream>>>(ga, nblk);
        }

        // bonds, 2 pair-closed chunks (rows [c*50K,+50K) U [100K+c*50K,+50K)):
        //   Tb = Hb + bf16(asum[v]-Hb[rev]) @ Wh_b^T ; Hb += relu(Tb @ Wf_b^T).
        // rev maps within each chunk, so later chunks never read updated rows.
        for (int c = 0; c < 2; ++c) {
            int nblk = cdiv(HALF, 128) * 2;
            ga.W = Whb; ga.ldw = DH; ga.base = Hb; ga.C = Tb;
            ga.Mloc = HALF; ga.part0 = HALF / 2; ga.off0 = c * 50000; ga.off1 = HALF + c * 50000;
            gemm128<AM_GDIFF, EPI_ADDBASE, 1, 0, 8><<<gsz2(nblk), 256, 0, stream>>>(ga, nblk);
            ga.A = Tb; ga.lda = DH; ga.W = Wfb; ga.base = Hb; ga.C = Hb;
            gemm128<AM_PLAIN, EPI_FUSE, 0, 0, 8><<<gsz2(nblk), 256, 0, stream>>>(ga, nblk);
        }
    }

    // ---- readout: out = relu(V @ Wo1^T + a_sum @ Wo2^T) ----
    seg_reduce<0><<<cdiv(NATOM, 4), 256, 0, stream>>>(Hb, rowptr, eid, asum, nullptr);
    {
        int nblk = cdiv(NATOM, 128) * 2;
        ga.Mloc = NATOM; ga.part0 = NATOM; ga.off0 = 0; ga.off1 = 0;
        ga.W = Wo1; ga.ldw = KVP; ga.C = T;
        gemm128<AM_VF32, EPI_NONE, 0, 0, 5><<<gsz2(nblk), 256, 0, stream>>>(ga, nblk);
        ga.W = Wo2; ga.ldw = DH; ga.base = T; ga.Cf = out;
        gemm128<AM_F32, EPI_RELUADD, 0, 1, 8><<<gsz2(nblk), 256, 0, stream>>>(ga, nblk);
    }
}